// Round 1
// baseline (1730.781 us; speedup 1.0000x reference)
//
#include <hip/hip_runtime.h>
#include <hip/hip_bf16.h>
#include <math.h>

#define NNODES 50000
#define FDIM   128
#define HIDDIM 64
#define NEDGES 800000
#define NB_SCAN 196   // ceil(50000/256)

__device__ __forceinline__ float leakyf(float x) { return x > 0.f ? x : 0.2f * x; }
__device__ __forceinline__ float eluf(float x)   { return x > 0.f ? x : expm1f(x); }

// ---------------- BatchNorm statistics ----------------
__global__ void k_bn_stats(const float* __restrict__ x, float* __restrict__ acc, int n) {
    int t = threadIdx.x;
    int f = t & 127, half = t >> 7;
    int rows_per_block = (n + gridDim.x - 1) / gridDim.x;
    int r0 = blockIdx.x * rows_per_block;
    int r1 = min(r0 + rows_per_block, n);
    float s = 0.f, s2 = 0.f;
    for (int r = r0 + half; r < r1; r += 2) {
        float v = x[(size_t)r * 128 + f];
        s += v; s2 += v * v;
    }
    __shared__ float ls[256], ls2[256];
    ls[t] = s; ls2[t] = s2;
    __syncthreads();
    if (t < 128) {
        s  = ls[t]  + ls[t + 128];
        s2 = ls2[t] + ls2[t + 128];
        atomicAdd(&acc[f], s);
        atomicAdd(&acc[128 + f], s2);
    }
}

__global__ void k_bn_final(const float* __restrict__ acc, const float* __restrict__ gamma,
                           const float* __restrict__ beta, float* __restrict__ ss, int n) {
    int f = threadIdx.x;
    if (f < 128) {
        float inv_n = 1.0f / (float)n;
        float mean = acc[f] * inv_n;
        float var  = acc[128 + f] * inv_n - mean * mean;
        float sc = gamma[f] * rsqrtf(var + 1e-5f);
        ss[f] = sc;
        ss[128 + f] = beta[f] - mean * sc;
    }
}

// ---------------- Fused BN-apply + encoder (2 GEMMs, ReLU) ----------------
// Wave-per-row: lane l owns output cols {2l,2l+1} of h, then col l of Cenc.
__launch_bounds__(512, 1)
__global__ void k_encoder(const float* __restrict__ x, const float* __restrict__ bnss,
                          const float* __restrict__ w1, const float* __restrict__ b1,
                          const float* __restrict__ w2, const float* __restrict__ b2,
                          float* __restrict__ Cenc, int n_nodes) {
    __shared__ float W1[128 * 128];
    __shared__ float W2[128 * 64];
    int t = threadIdx.x;
    for (int i = t; i < 128 * 128; i += 512) W1[i] = w1[i];
    for (int i = t; i < 128 * 64;  i += 512) W2[i] = w2[i];
    __syncthreads();
    int lane = t & 63, w = t >> 6;
    int nwaves = gridDim.x * 8;
    float sc0 = bnss[lane],      sh0 = bnss[128 + lane];
    float sc1 = bnss[64 + lane], sh1 = bnss[192 + lane];
    float b1v0 = b1[2 * lane], b1v1 = b1[2 * lane + 1];
    float b2v = b2[lane];
    for (int n = blockIdx.x * 8 + w; n < n_nodes; n += nwaves) {
        float x0 = x[(size_t)n * 128 + lane]      * sc0 + sh0;
        float x1 = x[(size_t)n * 128 + 64 + lane] * sc1 + sh1;
        float acc0 = b1v0, acc1 = b1v1;
#pragma unroll
        for (int k = 0; k < 64; ++k) {
            float xk = __shfl(x0, k, 64);
            float2 wv = *(const float2*)(W1 + k * 128 + 2 * lane);
            acc0 += xk * wv.x; acc1 += xk * wv.y;
        }
#pragma unroll
        for (int k = 0; k < 64; ++k) {
            float xk = __shfl(x1, k, 64);
            float2 wv = *(const float2*)(W1 + (64 + k) * 128 + 2 * lane);
            acc0 += xk * wv.x; acc1 += xk * wv.y;
        }
        float h0 = fmaxf(acc0, 0.f), h1 = fmaxf(acc1, 0.f);
        float acc2 = b2v;
#pragma unroll
        for (int k = 0; k < 64; ++k) {
            float hk0 = __shfl(h0, k, 64);
            float hk1 = __shfl(h1, k, 64);
            acc2 += hk0 * W2[(2 * k) * 64 + lane] + hk1 * W2[(2 * k + 1) * 64 + lane];
        }
        Cenc[(size_t)n * 64 + lane] = fmaxf(acc2, 0.f);
    }
}

// ---------------- GAT: xl = Cin @ W, plus per-node attention logits ----------------
__launch_bounds__(256)
__global__ void k_xl(const float* __restrict__ Cin, const float* __restrict__ Wg,
                     const float* __restrict__ attS, const float* __restrict__ attD,
                     float* __restrict__ xl, float* __restrict__ asrc, float* __restrict__ adst,
                     int n_nodes) {
    __shared__ float W[64 * 128];
    __shared__ float As[128], Ad[128];
    int t = threadIdx.x;
    for (int i = t; i < 64 * 128; i += 256) W[i] = Wg[i];
    if (t < 128) { As[t] = attS[t]; Ad[t] = attD[t]; }
    __syncthreads();
    int lane = t & 63, w = t >> 6;
    int nw = gridDim.x * 4;
    float aS0 = As[2 * lane], aS1 = As[2 * lane + 1];
    float aD0 = Ad[2 * lane], aD1 = Ad[2 * lane + 1];
    for (int n = blockIdx.x * 4 + w; n < n_nodes; n += nw) {
        float c = Cin[(size_t)n * 64 + lane];
        float acc0 = 0.f, acc1 = 0.f;
#pragma unroll
        for (int k = 0; k < 64; ++k) {
            float ck = __shfl(c, k, 64);
            float2 wv = *(const float2*)(W + k * 128 + 2 * lane);
            acc0 += ck * wv.x; acc1 += ck * wv.y;
        }
        *(float2*)(xl + (size_t)n * 128 + 2 * lane) = make_float2(acc0, acc1);
        float ps = acc0 * aS0 + acc1 * aS1;
        float pd = acc0 * aD0 + acc1 * aD1;
#pragma unroll
        for (int off = 16; off; off >>= 1) {
            ps += __shfl_xor(ps, off, 64);
            pd += __shfl_xor(pd, off, 64);
        }
        if ((lane & 31) == 0) {
            int h = lane >> 5;
            asrc[2 * n + h] = ps;
            adst[2 * n + h] = pd;
        }
    }
}

// ---------------- CSR build ----------------
__global__ void k_deg(const int* __restrict__ ei, int* __restrict__ deg, int ne) {
    int i = blockIdx.x * blockDim.x + threadIdx.x;
    if (i < ne) atomicAdd(&deg[ei[ne + i]], 1);
}

__global__ void k_scan_block(const int* __restrict__ deg, int* __restrict__ offs,
                             int* __restrict__ bsums, int n) {
    __shared__ int sd[256];
    int t = threadIdx.x;
    int i = blockIdx.x * 256 + t;
    int v = (i < n) ? deg[i] : 0;
    sd[t] = v;
    __syncthreads();
    for (int off = 1; off < 256; off <<= 1) {
        int u = (t >= off) ? sd[t - off] : 0;
        __syncthreads();
        sd[t] += u;
        __syncthreads();
    }
    if (i < n) offs[i] = sd[t] - v;      // local exclusive
    if (t == 255) bsums[blockIdx.x] = sd[255];
}

__global__ void k_scan_top(int* __restrict__ bsums, int nb) {
    __shared__ int sd[256];
    int t = threadIdx.x;
    int v = (t < nb) ? bsums[t] : 0;
    sd[t] = v;
    __syncthreads();
    for (int off = 1; off < 256; off <<= 1) {
        int u = (t >= off) ? sd[t - off] : 0;
        __syncthreads();
        sd[t] += u;
        __syncthreads();
    }
    if (t < nb) bsums[t] = sd[t] - v;    // exclusive block base
}

__global__ void k_scan_add(int* __restrict__ offs, const int* __restrict__ bsums,
                           int* __restrict__ cursor, int n, int ne) {
    int i = blockIdx.x * 256 + threadIdx.x;
    if (i < n) {
        int o = offs[i] + bsums[blockIdx.x];
        offs[i] = o;
        cursor[i] = o;
    }
    if (i == 0) offs[n] = ne;
}

__global__ void k_fill(const int* __restrict__ ei, int* __restrict__ cursor,
                       int* __restrict__ ssrc, int ne) {
    int i = blockIdx.x * blockDim.x + threadIdx.x;
    if (i < ne) {
        int d = ei[ne + i];
        int p = atomicAdd(&cursor[d], 1);
        ssrc[p] = ei[i];
    }
}

// ---------------- GAT aggregation: one wave per dst node, no atomics ----------------
__launch_bounds__(256)
__global__ void k_gat_agg(const float* __restrict__ Cin, const float* __restrict__ xl,
                          const float* __restrict__ asrc, const float* __restrict__ adst,
                          const int* __restrict__ offs, const int* __restrict__ ssrc,
                          const float* __restrict__ bias, float* __restrict__ Cout,
                          int n_nodes) {
    int wid = (blockIdx.x * blockDim.x + threadIdx.x) >> 6;
    int lane = threadIdx.x & 63;
    if (wid >= n_nodes) return;
    int n = wid;
    int h = lane >> 5;
    int beg = offs[n], end = offs[n + 1];
    float ad0 = adst[2 * n], ad1 = adst[2 * n + 1];
    float as0 = asrc[2 * n], as1 = asrc[2 * n + 1];
    float es0 = leakyf(as0 + ad0), es1 = leakyf(as1 + ad1);   // self-loop logits
    // pass 1: segment max (edges distributed across lanes)
    float m0 = es0, m1 = es1;
    for (int i = beg + lane; i < end; i += 64) {
        int s = ssrc[i];
        float2 a = *(const float2*)(asrc + 2 * s);
        m0 = fmaxf(m0, leakyf(a.x + ad0));
        m1 = fmaxf(m1, leakyf(a.y + ad1));
    }
#pragma unroll
    for (int off = 32; off; off >>= 1) {
        m0 = fmaxf(m0, __shfl_xor(m0, off, 64));
        m1 = fmaxf(m1, __shfl_xor(m1, off, 64));
    }
    float mh  = h ? m1 : m0;
    float adh = h ? ad1 : ad0;
    // pass 2: weighted aggregation (edge loop uniform across wave; lane owns 2 channels)
    float acc0 = 0.f, acc1 = 0.f, dn = 0.f;
    const float2* xl2 = (const float2*)xl;
    for (int i = beg; i < end; ++i) {
        int s = ssrc[i];
        float ash = asrc[2 * s + h];
        float ee = __expf(leakyf(ash + adh) - mh);
        float2 v = xl2[(size_t)s * 64 + lane];
        acc0 += ee * v.x; acc1 += ee * v.y; dn += ee;
    }
    { // self loop
        float esh = h ? es1 : es0;
        float ee = __expf(esh - mh);
        float2 v = xl2[(size_t)n * 64 + lane];
        acc0 += ee * v.x; acc1 += ee * v.y; dn += ee;
    }
    float inv = 1.0f / dn;
    float o0 = acc0 * inv, o1 = acc1 * inv;
    float p0 = __shfl_xor(o0, 32, 64);
    float p1 = __shfl_xor(o1, 32, 64);
    if (lane < 32) {
        int c0 = 2 * lane;
        float hv0 = eluf(0.5f * (o0 + p0) + bias[c0]);
        float hv1 = eluf(0.5f * (o1 + p1) + bias[c0 + 1]);
        float2 cv = *(const float2*)(Cin + (size_t)n * 64 + c0);
        *(float2*)(Cout + (size_t)n * 64 + c0) = make_float2(cv.x - hv0, cv.y - hv1);
    }
}

// ---------------- Decoder: [N,192] @ [192,64] -> leaky -> @ [64,1] ----------------
__launch_bounds__(256)
__global__ void k_dec(const float* __restrict__ Cenc, const float* __restrict__ CI,
                      const float* __restrict__ CU, const float* __restrict__ w1,
                      const float* __restrict__ b1, const float* __restrict__ w2,
                      const float* __restrict__ b2, float* __restrict__ out, int n_nodes) {
    __shared__ float W[192 * 64];
    __shared__ float W2s[64];
    int t = threadIdx.x;
    for (int i = t; i < 192 * 64; i += 256) W[i] = w1[i];
    if (t < 64) W2s[t] = w2[t];
    __syncthreads();
    int lane = t & 63, w = t >> 6;
    int nw = gridDim.x * 4;
    float b1v = b1[lane];
    float b2v = b2[0];
    for (int n = blockIdx.x * 4 + w; n < n_nodes; n += nw) {
        float f0 = Cenc[(size_t)n * 64 + lane];
        float f1 = CI[(size_t)n * 64 + lane];
        float f2 = CU[(size_t)n * 64 + lane];
        float acc = b1v;
#pragma unroll
        for (int k = 0; k < 64; ++k) acc += __shfl(f0, k, 64) * W[k * 64 + lane];
#pragma unroll
        for (int k = 0; k < 64; ++k) acc += __shfl(f1, k, 64) * W[(64 + k) * 64 + lane];
#pragma unroll
        for (int k = 0; k < 64; ++k) acc += __shfl(f2, k, 64) * W[(128 + k) * 64 + lane];
        float h2 = leakyf(acc);
        float p = h2 * W2s[lane];
#pragma unroll
        for (int off = 32; off; off >>= 1) p += __shfl_xor(p, off, 64);
        if (lane == 0) out[n] = p + b2v;
    }
}

// ---------------- Factor attention: leaky(x@W+b) row-softmax ----------------
__launch_bounds__(256)
__global__ void k_fa(const float* __restrict__ x, const float* __restrict__ w,
                     const float* __restrict__ b, float* __restrict__ attn, int n_nodes) {
    __shared__ float W[128 * 128];
    int t = threadIdx.x;
    for (int i = t; i < 128 * 128; i += 256) W[i] = w[i];
    __syncthreads();
    int lane = t & 63, wv = t >> 6;
    int nw = gridDim.x * 4;
    float bv0 = b[2 * lane], bv1 = b[2 * lane + 1];
    for (int n = blockIdx.x * 4 + wv; n < n_nodes; n += nw) {
        float x0 = x[(size_t)n * 128 + lane];
        float x1 = x[(size_t)n * 128 + 64 + lane];
        float a0 = bv0, a1 = bv1;
#pragma unroll
        for (int k = 0; k < 64; ++k) {
            float xk = __shfl(x0, k, 64);
            float2 wvv = *(const float2*)(W + k * 128 + 2 * lane);
            a0 += xk * wvv.x; a1 += xk * wvv.y;
        }
#pragma unroll
        for (int k = 0; k < 64; ++k) {
            float xk = __shfl(x1, k, 64);
            float2 wvv = *(const float2*)(W + (64 + k) * 128 + 2 * lane);
            a0 += xk * wvv.x; a1 += xk * wvv.y;
        }
        float u0 = leakyf(a0), u1 = leakyf(a1);
        float m = fmaxf(u0, u1);
#pragma unroll
        for (int off = 32; off; off >>= 1) m = fmaxf(m, __shfl_xor(m, off, 64));
        float p0 = __expf(u0 - m), p1 = __expf(u1 - m);
        float s = p0 + p1;
#pragma unroll
        for (int off = 32; off; off >>= 1) s += __shfl_xor(s, off, 64);
        float inv = 1.0f / s;
        *(float2*)(attn + (size_t)n * 128 + 2 * lane) = make_float2(p0 * inv, p1 * inv);
    }
}

extern "C" void kernel_launch(void* const* d_in, const int* in_sizes, int n_in,
                              void* d_out, int out_size, void* d_ws, size_t ws_size,
                              hipStream_t stream) {
    const float* x        = (const float*)d_in[0];
    const int*   ei_ind   = (const int*)d_in[1];
    const int*   ei_uni   = (const int*)d_in[2];
    const float* bn_gamma = (const float*)d_in[3];
    const float* bn_beta  = (const float*)d_in[4];
    const float* enc_w1   = (const float*)d_in[5];
    const float* enc_b1   = (const float*)d_in[6];
    const float* enc_w2   = (const float*)d_in[7];
    const float* enc_b2   = (const float*)d_in[8];
    const float* gi_w     = (const float*)d_in[9];
    const float* gi_as    = (const float*)d_in[10];
    const float* gi_ad    = (const float*)d_in[11];
    const float* gi_b     = (const float*)d_in[12];
    const float* gu_w     = (const float*)d_in[13];
    const float* gu_as    = (const float*)d_in[14];
    const float* gu_ad    = (const float*)d_in[15];
    const float* gu_b     = (const float*)d_in[16];
    const float* dec_w1   = (const float*)d_in[17];
    const float* dec_b1   = (const float*)d_in[18];
    const float* dec_w2   = (const float*)d_in[19];
    const float* dec_b2   = (const float*)d_in[20];
    const float* fa_w     = (const float*)d_in[21];
    const float* fa_b     = (const float*)d_in[22];

    const int N = NNODES, E = NEDGES;

    // workspace carve
    float* Cenc  = (float*)d_ws;
    float* C_I   = Cenc + (size_t)N * 64;
    float* C_U   = C_I + (size_t)N * 64;
    float* xl    = C_U + (size_t)N * 64;
    float* a_src = xl + (size_t)N * 128;
    float* a_dst = a_src + (size_t)N * 2;
    float* bnacc = a_dst + (size_t)N * 2;
    float* bnss  = bnacc + 256;
    int* deg    = (int*)(bnss + 256);
    int* offs   = deg + N;
    int* cursor = offs + N + 1;
    int* bsums  = cursor + N;
    int* ssrc   = bsums + 256;

    float* out_deep = (float*)d_out;
    float* out_attn = out_deep + N;

    // ---- BatchNorm stats ----
    hipMemsetAsync(bnacc, 0, 256 * sizeof(float), stream);
    k_bn_stats<<<256, 256, 0, stream>>>(x, bnacc, N);
    k_bn_final<<<1, 128, 0, stream>>>(bnacc, bn_gamma, bn_beta, bnss, N);

    // ---- Encoder (fused BN + 2 GEMMs) ----
    k_encoder<<<512, 512, 0, stream>>>(x, bnss, enc_w1, enc_b1, enc_w2, enc_b2, Cenc, N);

    // ---- Industry GAT ----
    k_xl<<<1024, 256, 0, stream>>>(Cenc, gi_w, gi_as, gi_ad, xl, a_src, a_dst, N);
    hipMemsetAsync(deg, 0, N * sizeof(int), stream);
    k_deg<<<(E + 255) / 256, 256, 0, stream>>>(ei_ind, deg, E);
    k_scan_block<<<NB_SCAN, 256, 0, stream>>>(deg, offs, bsums, N);
    k_scan_top<<<1, 256, 0, stream>>>(bsums, NB_SCAN);
    k_scan_add<<<NB_SCAN, 256, 0, stream>>>(offs, bsums, cursor, N, E);
    k_fill<<<(E + 255) / 256, 256, 0, stream>>>(ei_ind, cursor, ssrc, E);
    k_gat_agg<<<(N + 3) / 4, 256, 0, stream>>>(Cenc, xl, a_src, a_dst, offs, ssrc, gi_b, C_I, N);

    // ---- Universe GAT ----
    k_xl<<<1024, 256, 0, stream>>>(C_I, gu_w, gu_as, gu_ad, xl, a_src, a_dst, N);
    hipMemsetAsync(deg, 0, N * sizeof(int), stream);
    k_deg<<<(E + 255) / 256, 256, 0, stream>>>(ei_uni, deg, E);
    k_scan_block<<<NB_SCAN, 256, 0, stream>>>(deg, offs, bsums, N);
    k_scan_top<<<1, 256, 0, stream>>>(bsums, NB_SCAN);
    k_scan_add<<<NB_SCAN, 256, 0, stream>>>(offs, bsums, cursor, N, E);
    k_fill<<<(E + 255) / 256, 256, 0, stream>>>(ei_uni, cursor, ssrc, E);
    k_gat_agg<<<(N + 3) / 4, 256, 0, stream>>>(C_I, xl, a_src, a_dst, offs, ssrc, gu_b, C_U, N);

    // ---- Decoder + factor attention ----
    k_dec<<<1024, 256, 0, stream>>>(Cenc, C_I, C_U, dec_w1, dec_b1, dec_w2, dec_b2, out_deep, N);
    k_fa<<<1024, 256, 0, stream>>>(x, fa_w, fa_b, out_attn, N);
}

// Round 2
// 873.994 us; speedup vs baseline: 1.9803x; 1.9803x over previous
//
#include <hip/hip_runtime.h>
#include <hip/hip_bf16.h>
#include <math.h>

#define NNODES 50000
#define FDIM   128
#define HIDDIM 64
#define NEDGES 800000
#define NB_SCAN 196   // ceil(50000/256)
#define NBLK32 1563   // ceil(50000/32)

__device__ __forceinline__ float leakyf(float x) { return x > 0.f ? x : 0.2f * x; }
__device__ __forceinline__ float eluf(float x)   { return x > 0.f ? x : expm1f(x); }

#define FMA8(A, xv, wa, wb) \
    A[0] += xv * wa.x; A[1] += xv * wa.y; A[2] += xv * wa.z; A[3] += xv * wa.w; \
    A[4] += xv * wb.x; A[5] += xv * wb.y; A[6] += xv * wb.z; A[7] += xv * wb.w;

// ---------------- BatchNorm statistics ----------------
__global__ void k_bn_stats(const float* __restrict__ x, float* __restrict__ acc, int n) {
    int t = threadIdx.x;
    int f = t & 127, half = t >> 7;
    int rows_per_block = (n + gridDim.x - 1) / gridDim.x;
    int r0 = blockIdx.x * rows_per_block;
    int r1 = min(r0 + rows_per_block, n);
    float s = 0.f, s2 = 0.f;
    for (int r = r0 + half; r < r1; r += 2) {
        float v = x[(size_t)r * 128 + f];
        s += v; s2 += v * v;
    }
    __shared__ float ls[256], ls2[256];
    ls[t] = s; ls2[t] = s2;
    __syncthreads();
    if (t < 128) {
        s  = ls[t]  + ls[t + 128];
        s2 = ls2[t] + ls2[t + 128];
        atomicAdd(&acc[f], s);
        atomicAdd(&acc[128 + f], s2);
    }
}

__global__ void k_bn_final(const float* __restrict__ acc, const float* __restrict__ gamma,
                           const float* __restrict__ beta, float* __restrict__ ss, int n) {
    int f = threadIdx.x;
    if (f < 128) {
        float inv_n = 1.0f / (float)n;
        float mean = acc[f] * inv_n;
        float var  = acc[128 + f] * inv_n - mean * mean;
        float sc = gamma[f] * rsqrtf(var + 1e-5f);
        ss[f] = sc;
        ss[128 + f] = beta[f] - mean * sc;
    }
}

// ---------------- Fused BN-apply + encoder: tiled GEMM ----------------
// Block: 256 thr, 32 rows. Xs/Hs in LDS (pad 132), weights streamed from L2.
__launch_bounds__(256, 4)
__global__ void k_encoder(const float* __restrict__ x, const float* __restrict__ bnss,
                          const float* __restrict__ w1, const float* __restrict__ b1,
                          const float* __restrict__ w2, const float* __restrict__ b2,
                          float* __restrict__ Cenc, int n_nodes) {
    __shared__ float Xs[32][132];
    __shared__ float Hs[32][132];
    int t = threadIdx.x;
    int r0 = blockIdx.x * 32;
    // phase 0: load + BN apply
#pragma unroll
    for (int it = 0; it < 4; ++it) {
        int idx = (it * 256 + t) * 4;
        int row = idx >> 7, col = idx & 127;
        float4 v = make_float4(0.f, 0.f, 0.f, 0.f);
        if (r0 + row < n_nodes) v = *(const float4*)(x + (size_t)(r0 + row) * 128 + col);
        float4 sc = *(const float4*)(bnss + col);
        float4 sh = *(const float4*)(bnss + 128 + col);
        Xs[row][col + 0] = v.x * sc.x + sh.x;
        Xs[row][col + 1] = v.y * sc.y + sh.y;
        Xs[row][col + 2] = v.z * sc.z + sh.z;
        Xs[row][col + 3] = v.w * sc.w + sh.w;
    }
    __syncthreads();
    // phase 1: h = relu(Xn @ W1 + b1) -> Hs
    {
        int cg = t & 15, rg = t >> 4;
        int c0 = cg * 8, rr = rg * 2;
        float4 ba = *(const float4*)(b1 + c0);
        float4 bb = *(const float4*)(b1 + c0 + 4);
        float a0[8] = {ba.x, ba.y, ba.z, ba.w, bb.x, bb.y, bb.z, bb.w};
        float a1[8] = {ba.x, ba.y, ba.z, ba.w, bb.x, bb.y, bb.z, bb.w};
#pragma unroll 4
        for (int k = 0; k < 128; ++k) {
            float4 wa = *(const float4*)(w1 + k * 128 + c0);
            float4 wb = *(const float4*)(w1 + k * 128 + c0 + 4);
            float x0 = Xs[rr][k], x1 = Xs[rr + 1][k];
            FMA8(a0, x0, wa, wb)
            FMA8(a1, x1, wa, wb)
        }
#pragma unroll
        for (int j = 0; j < 8; ++j) {
            Hs[rr][c0 + j]     = fmaxf(a0[j], 0.f);
            Hs[rr + 1][c0 + j] = fmaxf(a1[j], 0.f);
        }
    }
    __syncthreads();
    // phase 2: Cenc = relu(Hs @ W2 + b2)
    {
        int cg = t & 7, rg = t >> 3;
        int c0 = cg * 8;
        float4 ba = *(const float4*)(b2 + c0);
        float4 bb = *(const float4*)(b2 + c0 + 4);
        float a[8] = {ba.x, ba.y, ba.z, ba.w, bb.x, bb.y, bb.z, bb.w};
#pragma unroll 4
        for (int k = 0; k < 128; ++k) {
            float4 wa = *(const float4*)(w2 + k * 64 + c0);
            float4 wb = *(const float4*)(w2 + k * 64 + c0 + 4);
            float hv = Hs[rg][k];
            FMA8(a, hv, wa, wb)
        }
        if (r0 + rg < n_nodes) {
            float* o = Cenc + (size_t)(r0 + rg) * 64 + c0;
            *(float4*)o       = make_float4(fmaxf(a[0], 0.f), fmaxf(a[1], 0.f), fmaxf(a[2], 0.f), fmaxf(a[3], 0.f));
            *(float4*)(o + 4) = make_float4(fmaxf(a[4], 0.f), fmaxf(a[5], 0.f), fmaxf(a[6], 0.f), fmaxf(a[7], 0.f));
        }
    }
}

// ---------------- GAT: xl = Cin @ W, fused per-node attention logits ----------------
__launch_bounds__(256, 4)
__global__ void k_xl(const float* __restrict__ Cin, const float* __restrict__ Wg,
                     const float* __restrict__ attS, const float* __restrict__ attD,
                     float* __restrict__ xl, float* __restrict__ asrc, float* __restrict__ adst,
                     int n_nodes) {
    __shared__ float Cs[32][68];
    int t = threadIdx.x;
    int r0 = blockIdx.x * 32;
#pragma unroll
    for (int it = 0; it < 2; ++it) {
        int idx = (it * 256 + t) * 4;
        int row = idx >> 6, col = idx & 63;
        float4 v = make_float4(0.f, 0.f, 0.f, 0.f);
        if (r0 + row < n_nodes) v = *(const float4*)(Cin + (size_t)(r0 + row) * 64 + col);
        Cs[row][col + 0] = v.x; Cs[row][col + 1] = v.y;
        Cs[row][col + 2] = v.z; Cs[row][col + 3] = v.w;
    }
    __syncthreads();
    int cg = t & 15, rg = t >> 4;
    int c0 = cg * 8, rr = rg * 2;
    int head = cg >> 3, hc0 = (cg & 7) * 8;
    float a0[8] = {0.f}, a1[8] = {0.f};
#pragma unroll 4
    for (int k = 0; k < 64; ++k) {
        float4 wa = *(const float4*)(Wg + k * 128 + c0);
        float4 wb = *(const float4*)(Wg + k * 128 + c0 + 4);
        float x0 = Cs[rr][k], x1 = Cs[rr + 1][k];
        FMA8(a0, x0, wa, wb)
        FMA8(a1, x1, wa, wb)
    }
    // write xl
    if (r0 + rr < n_nodes) {
        float* o = xl + (size_t)(r0 + rr) * 128 + c0;
        *(float4*)o       = make_float4(a0[0], a0[1], a0[2], a0[3]);
        *(float4*)(o + 4) = make_float4(a0[4], a0[5], a0[6], a0[7]);
    }
    if (r0 + rr + 1 < n_nodes) {
        float* o = xl + (size_t)(r0 + rr + 1) * 128 + c0;
        *(float4*)o       = make_float4(a1[0], a1[1], a1[2], a1[3]);
        *(float4*)(o + 4) = make_float4(a1[4], a1[5], a1[6], a1[7]);
    }
    // attention logits: per (row, head) dot with att vectors
    float4 sa = *(const float4*)(attS + head * 64 + hc0);
    float4 sb = *(const float4*)(attS + head * 64 + hc0 + 4);
    float4 da = *(const float4*)(attD + head * 64 + hc0);
    float4 db = *(const float4*)(attD + head * 64 + hc0 + 4);
    float ps0 = a0[0]*sa.x + a0[1]*sa.y + a0[2]*sa.z + a0[3]*sa.w
              + a0[4]*sb.x + a0[5]*sb.y + a0[6]*sb.z + a0[7]*sb.w;
    float pd0 = a0[0]*da.x + a0[1]*da.y + a0[2]*da.z + a0[3]*da.w
              + a0[4]*db.x + a0[5]*db.y + a0[6]*db.z + a0[7]*db.w;
    float ps1 = a1[0]*sa.x + a1[1]*sa.y + a1[2]*sa.z + a1[3]*sa.w
              + a1[4]*sb.x + a1[5]*sb.y + a1[6]*sb.z + a1[7]*sb.w;
    float pd1 = a1[0]*da.x + a1[1]*da.y + a1[2]*da.z + a1[3]*da.w
              + a1[4]*db.x + a1[5]*db.y + a1[6]*db.z + a1[7]*db.w;
#pragma unroll
    for (int off = 1; off < 8; off <<= 1) {
        ps0 += __shfl_xor(ps0, off, 64); pd0 += __shfl_xor(pd0, off, 64);
        ps1 += __shfl_xor(ps1, off, 64); pd1 += __shfl_xor(pd1, off, 64);
    }
    if ((cg & 7) == 0) {
        if (r0 + rr < n_nodes)     { asrc[2*(r0+rr)   + head] = ps0; adst[2*(r0+rr)   + head] = pd0; }
        if (r0 + rr + 1 < n_nodes) { asrc[2*(r0+rr+1) + head] = ps1; adst[2*(r0+rr+1) + head] = pd1; }
    }
}

// ---------------- CSR build ----------------
__global__ void k_deg(const int* __restrict__ ei, int* __restrict__ deg, int ne) {
    int i = blockIdx.x * blockDim.x + threadIdx.x;
    if (i < ne) atomicAdd(&deg[ei[ne + i]], 1);
}

__global__ void k_scan_block(const int* __restrict__ deg, int* __restrict__ offs,
                             int* __restrict__ bsums, int n) {
    __shared__ int sd[256];
    int t = threadIdx.x;
    int i = blockIdx.x * 256 + t;
    int v = (i < n) ? deg[i] : 0;
    sd[t] = v;
    __syncthreads();
    for (int off = 1; off < 256; off <<= 1) {
        int u = (t >= off) ? sd[t - off] : 0;
        __syncthreads();
        sd[t] += u;
        __syncthreads();
    }
    if (i < n) offs[i] = sd[t] - v;
    if (t == 255) bsums[blockIdx.x] = sd[255];
}

__global__ void k_scan_top(int* __restrict__ bsums, int nb) {
    __shared__ int sd[256];
    int t = threadIdx.x;
    int v = (t < nb) ? bsums[t] : 0;
    sd[t] = v;
    __syncthreads();
    for (int off = 1; off < 256; off <<= 1) {
        int u = (t >= off) ? sd[t - off] : 0;
        __syncthreads();
        sd[t] += u;
        __syncthreads();
    }
    if (t < nb) bsums[t] = sd[t] - v;
}

__global__ void k_scan_add(int* __restrict__ offs, const int* __restrict__ bsums,
                           int* __restrict__ cursor, int n, int ne) {
    int i = blockIdx.x * 256 + threadIdx.x;
    if (i < n) {
        int o = offs[i] + bsums[blockIdx.x];
        offs[i] = o;
        cursor[i] = o;
    }
    if (i == 0) offs[n] = ne;
}

__global__ void k_fill(const int* __restrict__ ei, int* __restrict__ cursor,
                       int* __restrict__ ssrc, int ne) {
    int i = blockIdx.x * blockDim.x + threadIdx.x;
    if (i < ne) {
        int d = ei[ne + i];
        int p = atomicAdd(&cursor[d], 1);
        ssrc[p] = ei[i];
    }
}

// ---------------- GAT aggregation: one wave per dst node, no atomics ----------------
__launch_bounds__(256)
__global__ void k_gat_agg(const float* __restrict__ Cin, const float* __restrict__ xl,
                          const float* __restrict__ asrc, const float* __restrict__ adst,
                          const int* __restrict__ offs, const int* __restrict__ ssrc,
                          const float* __restrict__ bias, float* __restrict__ Cout,
                          int n_nodes) {
    int wid = (blockIdx.x * blockDim.x + threadIdx.x) >> 6;
    int lane = threadIdx.x & 63;
    if (wid >= n_nodes) return;
    int n = wid;
    int h = lane >> 5;
    int beg = offs[n], end = offs[n + 1];
    float ad0 = adst[2 * n], ad1 = adst[2 * n + 1];
    float as0 = asrc[2 * n], as1 = asrc[2 * n + 1];
    float es0 = leakyf(as0 + ad0), es1 = leakyf(as1 + ad1);
    float m0 = es0, m1 = es1;
    for (int i = beg + lane; i < end; i += 64) {
        int s = ssrc[i];
        float2 a = *(const float2*)(asrc + 2 * s);
        m0 = fmaxf(m0, leakyf(a.x + ad0));
        m1 = fmaxf(m1, leakyf(a.y + ad1));
    }
#pragma unroll
    for (int off = 32; off; off >>= 1) {
        m0 = fmaxf(m0, __shfl_xor(m0, off, 64));
        m1 = fmaxf(m1, __shfl_xor(m1, off, 64));
    }
    float mh  = h ? m1 : m0;
    float adh = h ? ad1 : ad0;
    float acc0 = 0.f, acc1 = 0.f, dn = 0.f;
    const float2* xl2 = (const float2*)xl;
    for (int i = beg; i < end; ++i) {
        int s = ssrc[i];
        float ash = asrc[2 * s + h];
        float ee = __expf(leakyf(ash + adh) - mh);
        float2 v = xl2[(size_t)s * 64 + lane];
        acc0 += ee * v.x; acc1 += ee * v.y; dn += ee;
    }
    {
        float esh = h ? es1 : es0;
        float ee = __expf(esh - mh);
        float2 v = xl2[(size_t)n * 64 + lane];
        acc0 += ee * v.x; acc1 += ee * v.y; dn += ee;
    }
    float inv = 1.0f / dn;
    float o0 = acc0 * inv, o1 = acc1 * inv;
    float p0 = __shfl_xor(o0, 32, 64);
    float p1 = __shfl_xor(o1, 32, 64);
    if (lane < 32) {
        int c0 = 2 * lane;
        float hv0 = eluf(0.5f * (o0 + p0) + bias[c0]);
        float hv1 = eluf(0.5f * (o1 + p1) + bias[c0 + 1]);
        float2 cv = *(const float2*)(Cin + (size_t)n * 64 + c0);
        *(float2*)(Cout + (size_t)n * 64 + c0) = make_float2(cv.x - hv0, cv.y - hv1);
    }
}

// ---------------- Decoder: [N,192] @ [192,64] -> leaky -> @ [64,1] ----------------
__launch_bounds__(256, 4)
__global__ void k_dec(const float* __restrict__ Cenc, const float* __restrict__ CI,
                      const float* __restrict__ CU, const float* __restrict__ w1,
                      const float* __restrict__ b1, const float* __restrict__ w2,
                      const float* __restrict__ b2, float* __restrict__ out, int n_nodes) {
    __shared__ float Fs[32][196];
    int t = threadIdx.x;
    int r0 = blockIdx.x * 32;
    const float* srcs[3] = {Cenc, CI, CU};
#pragma unroll
    for (int s = 0; s < 3; ++s) {
        const float* src = srcs[s];
#pragma unroll
        for (int it = 0; it < 2; ++it) {
            int idx = (it * 256 + t) * 4;
            int row = idx >> 6, col = idx & 63;
            float4 v = make_float4(0.f, 0.f, 0.f, 0.f);
            if (r0 + row < n_nodes) v = *(const float4*)(src + (size_t)(r0 + row) * 64 + col);
            Fs[row][s * 64 + col + 0] = v.x; Fs[row][s * 64 + col + 1] = v.y;
            Fs[row][s * 64 + col + 2] = v.z; Fs[row][s * 64 + col + 3] = v.w;
        }
    }
    __syncthreads();
    int cg = t & 7, rg = t >> 3;
    int c0 = cg * 8;
    float4 ba = *(const float4*)(b1 + c0);
    float4 bb = *(const float4*)(b1 + c0 + 4);
    float a[8] = {ba.x, ba.y, ba.z, ba.w, bb.x, bb.y, bb.z, bb.w};
#pragma unroll 4
    for (int k = 0; k < 192; ++k) {
        float4 wa = *(const float4*)(w1 + k * 64 + c0);
        float4 wb = *(const float4*)(w1 + k * 64 + c0 + 4);
        float fv = Fs[rg][k];
        FMA8(a, fv, wa, wb)
    }
    float4 w2a = *(const float4*)(w2 + c0);
    float4 w2b = *(const float4*)(w2 + c0 + 4);
    float p = leakyf(a[0])*w2a.x + leakyf(a[1])*w2a.y + leakyf(a[2])*w2a.z + leakyf(a[3])*w2a.w
            + leakyf(a[4])*w2b.x + leakyf(a[5])*w2b.y + leakyf(a[6])*w2b.z + leakyf(a[7])*w2b.w;
#pragma unroll
    for (int off = 1; off < 8; off <<= 1) p += __shfl_xor(p, off, 64);
    if (cg == 0 && r0 + rg < n_nodes) out[r0 + rg] = p + b2[0];
}

// ---------------- Factor attention: leaky(x@W+b) row-softmax, in-register ----------------
__launch_bounds__(256, 4)
__global__ void k_fa(const float* __restrict__ x, const float* __restrict__ w,
                     const float* __restrict__ b, float* __restrict__ attn, int n_nodes) {
    __shared__ float Xs[32][132];
    int t = threadIdx.x;
    int r0 = blockIdx.x * 32;
#pragma unroll
    for (int it = 0; it < 4; ++it) {
        int idx = (it * 256 + t) * 4;
        int row = idx >> 7, col = idx & 127;
        float4 v = make_float4(0.f, 0.f, 0.f, 0.f);
        if (r0 + row < n_nodes) v = *(const float4*)(x + (size_t)(r0 + row) * 128 + col);
        Xs[row][col + 0] = v.x; Xs[row][col + 1] = v.y;
        Xs[row][col + 2] = v.z; Xs[row][col + 3] = v.w;
    }
    __syncthreads();
    int cg = t & 15, rg = t >> 4;
    int c0 = cg * 8, rr = rg * 2;
    float4 ba = *(const float4*)(b + c0);
    float4 bb = *(const float4*)(b + c0 + 4);
    float a0[8] = {ba.x, ba.y, ba.z, ba.w, bb.x, bb.y, bb.z, bb.w};
    float a1[8] = {ba.x, ba.y, ba.z, ba.w, bb.x, bb.y, bb.z, bb.w};
#pragma unroll 4
    for (int k = 0; k < 128; ++k) {
        float4 wa = *(const float4*)(w + k * 128 + c0);
        float4 wb = *(const float4*)(w + k * 128 + c0 + 4);
        float x0 = Xs[rr][k], x1 = Xs[rr + 1][k];
        FMA8(a0, x0, wa, wb)
        FMA8(a1, x1, wa, wb)
    }
    // leaky + row softmax (16 threads share a row-pair; shfl_xor within 16-lane group)
    float m0 = -1e30f, m1 = -1e30f;
#pragma unroll
    for (int j = 0; j < 8; ++j) {
        a0[j] = leakyf(a0[j]); a1[j] = leakyf(a1[j]);
        m0 = fmaxf(m0, a0[j]); m1 = fmaxf(m1, a1[j]);
    }
#pragma unroll
    for (int off = 1; off < 16; off <<= 1) {
        m0 = fmaxf(m0, __shfl_xor(m0, off, 64));
        m1 = fmaxf(m1, __shfl_xor(m1, off, 64));
    }
    float s0 = 0.f, s1 = 0.f;
#pragma unroll
    for (int j = 0; j < 8; ++j) {
        a0[j] = __expf(a0[j] - m0); s0 += a0[j];
        a1[j] = __expf(a1[j] - m1); s1 += a1[j];
    }
#pragma unroll
    for (int off = 1; off < 16; off <<= 1) {
        s0 += __shfl_xor(s0, off, 64);
        s1 += __shfl_xor(s1, off, 64);
    }
    float i0 = 1.0f / s0, i1 = 1.0f / s1;
    if (r0 + rr < n_nodes) {
        float* o = attn + (size_t)(r0 + rr) * 128 + c0;
        *(float4*)o       = make_float4(a0[0]*i0, a0[1]*i0, a0[2]*i0, a0[3]*i0);
        *(float4*)(o + 4) = make_float4(a0[4]*i0, a0[5]*i0, a0[6]*i0, a0[7]*i0);
    }
    if (r0 + rr + 1 < n_nodes) {
        float* o = attn + (size_t)(r0 + rr + 1) * 128 + c0;
        *(float4*)o       = make_float4(a1[0]*i1, a1[1]*i1, a1[2]*i1, a1[3]*i1);
        *(float4*)(o + 4) = make_float4(a1[4]*i1, a1[5]*i1, a1[6]*i1, a1[7]*i1);
    }
}

extern "C" void kernel_launch(void* const* d_in, const int* in_sizes, int n_in,
                              void* d_out, int out_size, void* d_ws, size_t ws_size,
                              hipStream_t stream) {
    const float* x        = (const float*)d_in[0];
    const int*   ei_ind   = (const int*)d_in[1];
    const int*   ei_uni   = (const int*)d_in[2];
    const float* bn_gamma = (const float*)d_in[3];
    const float* bn_beta  = (const float*)d_in[4];
    const float* enc_w1   = (const float*)d_in[5];
    const float* enc_b1   = (const float*)d_in[6];
    const float* enc_w2   = (const float*)d_in[7];
    const float* enc_b2   = (const float*)d_in[8];
    const float* gi_w     = (const float*)d_in[9];
    const float* gi_as    = (const float*)d_in[10];
    const float* gi_ad    = (const float*)d_in[11];
    const float* gi_b     = (const float*)d_in[12];
    const float* gu_w     = (const float*)d_in[13];
    const float* gu_as    = (const float*)d_in[14];
    const float* gu_ad    = (const float*)d_in[15];
    const float* gu_b     = (const float*)d_in[16];
    const float* dec_w1   = (const float*)d_in[17];
    const float* dec_b1   = (const float*)d_in[18];
    const float* dec_w2   = (const float*)d_in[19];
    const float* dec_b2   = (const float*)d_in[20];
    const float* fa_w     = (const float*)d_in[21];
    const float* fa_b     = (const float*)d_in[22];

    const int N = NNODES, E = NEDGES;

    float* Cenc  = (float*)d_ws;
    float* C_I   = Cenc + (size_t)N * 64;
    float* C_U   = C_I + (size_t)N * 64;
    float* xl    = C_U + (size_t)N * 64;
    float* a_src = xl + (size_t)N * 128;
    float* a_dst = a_src + (size_t)N * 2;
    float* bnacc = a_dst + (size_t)N * 2;
    float* bnss  = bnacc + 256;
    int* deg    = (int*)(bnss + 256);
    int* offs   = deg + N;
    int* cursor = offs + N + 1;
    int* bsums  = cursor + N;
    int* ssrc   = bsums + 256;

    float* out_deep = (float*)d_out;
    float* out_attn = out_deep + N;

    // ---- BatchNorm stats ----
    hipMemsetAsync(bnacc, 0, 256 * sizeof(float), stream);
    k_bn_stats<<<256, 256, 0, stream>>>(x, bnacc, N);
    k_bn_final<<<1, 128, 0, stream>>>(bnacc, bn_gamma, bn_beta, bnss, N);

    // ---- Encoder ----
    k_encoder<<<NBLK32, 256, 0, stream>>>(x, bnss, enc_w1, enc_b1, enc_w2, enc_b2, Cenc, N);

    // ---- Industry GAT ----
    k_xl<<<NBLK32, 256, 0, stream>>>(Cenc, gi_w, gi_as, gi_ad, xl, a_src, a_dst, N);
    hipMemsetAsync(deg, 0, N * sizeof(int), stream);
    k_deg<<<(E + 255) / 256, 256, 0, stream>>>(ei_ind, deg, E);
    k_scan_block<<<NB_SCAN, 256, 0, stream>>>(deg, offs, bsums, N);
    k_scan_top<<<1, 256, 0, stream>>>(bsums, NB_SCAN);
    k_scan_add<<<NB_SCAN, 256, 0, stream>>>(offs, bsums, cursor, N, E);
    k_fill<<<(E + 255) / 256, 256, 0, stream>>>(ei_ind, cursor, ssrc, E);
    k_gat_agg<<<(N + 3) / 4, 256, 0, stream>>>(Cenc, xl, a_src, a_dst, offs, ssrc, gi_b, C_I, N);

    // ---- Universe GAT ----
    k_xl<<<NBLK32, 256, 0, stream>>>(C_I, gu_w, gu_as, gu_ad, xl, a_src, a_dst, N);
    hipMemsetAsync(deg, 0, N * sizeof(int), stream);
    k_deg<<<(E + 255) / 256, 256, 0, stream>>>(ei_uni, deg, E);
    k_scan_block<<<NB_SCAN, 256, 0, stream>>>(deg, offs, bsums, N);
    k_scan_top<<<1, 256, 0, stream>>>(bsums, NB_SCAN);
    k_scan_add<<<NB_SCAN, 256, 0, stream>>>(offs, bsums, cursor, N, E);
    k_fill<<<(E + 255) / 256, 256, 0, stream>>>(ei_uni, cursor, ssrc, E);
    k_gat_agg<<<(N + 3) / 4, 256, 0, stream>>>(C_I, xl, a_src, a_dst, offs, ssrc, gu_b, C_U, N);

    // ---- Decoder + factor attention ----
    k_dec<<<NBLK32, 256, 0, stream>>>(Cenc, C_I, C_U, dec_w1, dec_b1, dec_w2, dec_b2, out_deep, N);
    k_fa<<<NBLK32, 256, 0, stream>>>(x, fa_w, fa_b, out_attn, N);
}

// Round 3
// 776.825 us; speedup vs baseline: 2.2280x; 1.1251x over previous
//
#include <hip/hip_runtime.h>
#include <hip/hip_bf16.h>
#include <math.h>

#define NNODES 50000
#define FDIM   128
#define HIDDIM 64
#define NEDGES 800000
#define NBLK64 782          // ceil(50000/64)
#define N2     (2*NNODES)
#define NB2_SCAN 391        // ceil(100000/256)

__device__ __forceinline__ float leakyf(float x) { return x > 0.f ? x : 0.2f * x; }
__device__ __forceinline__ float eluf(float x)   { return x > 0.f ? x : expm1f(x); }

#define FMA8(A, xv, wa, wb) \
    A[0] += xv * wa.x; A[1] += xv * wa.y; A[2] += xv * wa.z; A[3] += xv * wa.w; \
    A[4] += xv * wb.x; A[5] += xv * wb.y; A[6] += xv * wb.z; A[7] += xv * wb.w;

// ---------------- BatchNorm statistics ----------------
__global__ void k_bn_stats(const float* __restrict__ x, float* __restrict__ acc, int n) {
    int t = threadIdx.x;
    int f = t & 127, half = t >> 7;
    int rows_per_block = (n + gridDim.x - 1) / gridDim.x;
    int r0 = blockIdx.x * rows_per_block;
    int r1 = min(r0 + rows_per_block, n);
    float s = 0.f, s2 = 0.f;
    for (int r = r0 + half; r < r1; r += 2) {
        float v = x[(size_t)r * 128 + f];
        s += v; s2 += v * v;
    }
    __shared__ float ls[256], ls2[256];
    ls[t] = s; ls2[t] = s2;
    __syncthreads();
    if (t < 128) {
        s  = ls[t]  + ls[t + 128];
        s2 = ls2[t] + ls2[t + 128];
        atomicAdd(&acc[f], s);
        atomicAdd(&acc[128 + f], s2);
    }
}

__global__ void k_bn_final(const float* __restrict__ acc, const float* __restrict__ gamma,
                           const float* __restrict__ beta, float* __restrict__ ss, int n) {
    int f = threadIdx.x;
    if (f < 128) {
        float inv_n = 1.0f / (float)n;
        float mean = acc[f] * inv_n;
        float var  = acc[128 + f] * inv_n - mean * mean;
        float sc = gamma[f] * rsqrtf(var + 1e-5f);
        ss[f] = sc;
        ss[128 + f] = beta[f] - mean * sc;
    }
}

// ---------------- Fused BN + encoder, 64-row tile, prefetched weights ----------------
__launch_bounds__(256, 4)
__global__ void k_encoder(const float* __restrict__ x, const float* __restrict__ bnss,
                          const float* __restrict__ w1, const float* __restrict__ b1,
                          const float* __restrict__ w2, const float* __restrict__ b2,
                          float* __restrict__ Cenc, int n_nodes) {
    __shared__ float Xs[64][133];    // X tile, then reused for H tile
    int t = threadIdx.x;
    int r0 = blockIdx.x * 64;
    // stage 64x128 with BN applied
#pragma unroll
    for (int it = 0; it < 8; ++it) {
        int idx = it * 256 + t;
        int row = idx >> 5;
        int col = (idx & 31) * 4;
        float4 v = make_float4(0.f, 0.f, 0.f, 0.f);
        if (r0 + row < n_nodes) v = *(const float4*)(x + (size_t)(r0 + row) * 128 + col);
        float4 sc = *(const float4*)(bnss + col);
        float4 sh = *(const float4*)(bnss + 128 + col);
        Xs[row][col + 0] = v.x * sc.x + sh.x;
        Xs[row][col + 1] = v.y * sc.y + sh.y;
        Xs[row][col + 2] = v.z * sc.z + sh.z;
        Xs[row][col + 3] = v.w * sc.w + sh.w;
    }
    __syncthreads();
    // phase 1: H = relu(X @ W1 + b1), thread = 4 rows x 8 cols
    int cg = t & 15, rsub = t >> 4;
    int c0 = cg * 8, rbase = rsub * 4;
    float acc[4][8];
    {
        float4 ba = *(const float4*)(b1 + c0);
        float4 bb = *(const float4*)(b1 + c0 + 4);
#pragma unroll
        for (int j = 0; j < 4; ++j) {
            acc[j][0] = ba.x; acc[j][1] = ba.y; acc[j][2] = ba.z; acc[j][3] = ba.w;
            acc[j][4] = bb.x; acc[j][5] = bb.y; acc[j][6] = bb.z; acc[j][7] = bb.w;
        }
    }
    {
        float4 wA[4], wB[4];
#pragma unroll
        for (int d = 0; d < 4; ++d) {
            wA[d] = *(const float4*)(w1 + d * 128 + c0);
            wB[d] = *(const float4*)(w1 + d * 128 + c0 + 4);
        }
        for (int k = 0; k < 128; k += 4) {
#pragma unroll
            for (int d = 0; d < 4; ++d) {
                int kn = (k + 4 + d) & 127;
                float4 na = *(const float4*)(w1 + kn * 128 + c0);
                float4 nb = *(const float4*)(w1 + kn * 128 + c0 + 4);
                float x0 = Xs[rbase + 0][k + d];
                float x1 = Xs[rbase + 1][k + d];
                float x2 = Xs[rbase + 2][k + d];
                float x3 = Xs[rbase + 3][k + d];
                FMA8(acc[0], x0, wA[d], wB[d])
                FMA8(acc[1], x1, wA[d], wB[d])
                FMA8(acc[2], x2, wA[d], wB[d])
                FMA8(acc[3], x3, wA[d], wB[d])
                wA[d] = na; wB[d] = nb;
            }
        }
    }
    __syncthreads();   // everyone done reading X
#pragma unroll
    for (int j = 0; j < 4; ++j)
#pragma unroll
        for (int i = 0; i < 8; ++i)
            Xs[rbase + j][c0 + i] = fmaxf(acc[j][i], 0.f);
    __syncthreads();
    // phase 2: Cenc = relu(H @ W2 + b2), thread = 2 rows x 8 cols
    int cg2 = t & 7, rs2 = t >> 3;
    int c2 = cg2 * 8, r2 = rs2 * 2;
    float a2[2][8];
    {
        float4 ba = *(const float4*)(b2 + c2);
        float4 bb = *(const float4*)(b2 + c2 + 4);
#pragma unroll
        for (int j = 0; j < 2; ++j) {
            a2[j][0] = ba.x; a2[j][1] = ba.y; a2[j][2] = ba.z; a2[j][3] = ba.w;
            a2[j][4] = bb.x; a2[j][5] = bb.y; a2[j][6] = bb.z; a2[j][7] = bb.w;
        }
    }
    {
        float4 wA[4], wB[4];
#pragma unroll
        for (int d = 0; d < 4; ++d) {
            wA[d] = *(const float4*)(w2 + d * 64 + c2);
            wB[d] = *(const float4*)(w2 + d * 64 + c2 + 4);
        }
        for (int k = 0; k < 128; k += 4) {
#pragma unroll
            for (int d = 0; d < 4; ++d) {
                int kn = (k + 4 + d) & 127;
                float4 na = *(const float4*)(w2 + kn * 64 + c2);
                float4 nb = *(const float4*)(w2 + kn * 64 + c2 + 4);
                float h0 = Xs[r2 + 0][k + d];
                float h1 = Xs[r2 + 1][k + d];
                FMA8(a2[0], h0, wA[d], wB[d])
                FMA8(a2[1], h1, wA[d], wB[d])
                wA[d] = na; wB[d] = nb;
            }
        }
    }
#pragma unroll
    for (int j = 0; j < 2; ++j) {
        int row = r0 + r2 + j;
        if (row < n_nodes) {
            float* o = Cenc + (size_t)row * 64 + c2;
            *(float4*)o       = make_float4(fmaxf(a2[j][0], 0.f), fmaxf(a2[j][1], 0.f),
                                            fmaxf(a2[j][2], 0.f), fmaxf(a2[j][3], 0.f));
            *(float4*)(o + 4) = make_float4(fmaxf(a2[j][4], 0.f), fmaxf(a2[j][5], 0.f),
                                            fmaxf(a2[j][6], 0.f), fmaxf(a2[j][7], 0.f));
        }
    }
}

// ---------------- GAT: xl = Cin @ W + fused attention logits ----------------
__launch_bounds__(256, 4)
__global__ void k_xl(const float* __restrict__ Cin, const float* __restrict__ Wg,
                     const float* __restrict__ attS, const float* __restrict__ attD,
                     float* __restrict__ xl, float* __restrict__ asrc, float* __restrict__ adst,
                     int n_nodes) {
    __shared__ float Cs[64][65];
    int t = threadIdx.x;
    int r0 = blockIdx.x * 64;
#pragma unroll
    for (int it = 0; it < 4; ++it) {
        int idx = it * 256 + t;
        int row = idx >> 4;
        int col = (idx & 15) * 4;
        float4 v = make_float4(0.f, 0.f, 0.f, 0.f);
        if (r0 + row < n_nodes) v = *(const float4*)(Cin + (size_t)(r0 + row) * 64 + col);
        Cs[row][col + 0] = v.x; Cs[row][col + 1] = v.y;
        Cs[row][col + 2] = v.z; Cs[row][col + 3] = v.w;
    }
    __syncthreads();
    int cg = t & 15, rsub = t >> 4;
    int c0 = cg * 8, rbase = rsub * 4;
    float acc[4][8];
#pragma unroll
    for (int j = 0; j < 4; ++j)
#pragma unroll
        for (int i = 0; i < 8; ++i) acc[j][i] = 0.f;
    {
        float4 wA[4], wB[4];
#pragma unroll
        for (int d = 0; d < 4; ++d) {
            wA[d] = *(const float4*)(Wg + d * 128 + c0);
            wB[d] = *(const float4*)(Wg + d * 128 + c0 + 4);
        }
        for (int k = 0; k < 64; k += 4) {
#pragma unroll
            for (int d = 0; d < 4; ++d) {
                int kn = (k + 4 + d) & 63;
                float4 na = *(const float4*)(Wg + kn * 128 + c0);
                float4 nb = *(const float4*)(Wg + kn * 128 + c0 + 4);
                float x0 = Cs[rbase + 0][k + d];
                float x1 = Cs[rbase + 1][k + d];
                float x2 = Cs[rbase + 2][k + d];
                float x3 = Cs[rbase + 3][k + d];
                FMA8(acc[0], x0, wA[d], wB[d])
                FMA8(acc[1], x1, wA[d], wB[d])
                FMA8(acc[2], x2, wA[d], wB[d])
                FMA8(acc[3], x3, wA[d], wB[d])
                wA[d] = na; wB[d] = nb;
            }
        }
    }
    // write xl
#pragma unroll
    for (int j = 0; j < 4; ++j) {
        int row = r0 + rbase + j;
        if (row < n_nodes) {
            float* o = xl + (size_t)row * 128 + c0;
            *(float4*)o       = make_float4(acc[j][0], acc[j][1], acc[j][2], acc[j][3]);
            *(float4*)(o + 4) = make_float4(acc[j][4], acc[j][5], acc[j][6], acc[j][7]);
        }
    }
    // attention logits
    int head = cg >> 3;
    const float* as_ = attS + head * 64 + (cg & 7) * 8;
    const float* ad_ = attD + head * 64 + (cg & 7) * 8;
    float4 sa = *(const float4*)as_,       sb = *(const float4*)(as_ + 4);
    float4 da = *(const float4*)ad_,       db = *(const float4*)(ad_ + 4);
    float ps[4], pd[4];
#pragma unroll
    for (int j = 0; j < 4; ++j) {
        ps[j] = acc[j][0]*sa.x + acc[j][1]*sa.y + acc[j][2]*sa.z + acc[j][3]*sa.w
              + acc[j][4]*sb.x + acc[j][5]*sb.y + acc[j][6]*sb.z + acc[j][7]*sb.w;
        pd[j] = acc[j][0]*da.x + acc[j][1]*da.y + acc[j][2]*da.z + acc[j][3]*da.w
              + acc[j][4]*db.x + acc[j][5]*db.y + acc[j][6]*db.z + acc[j][7]*db.w;
#pragma unroll
        for (int off = 1; off < 8; off <<= 1) {
            ps[j] += __shfl_xor(ps[j], off, 64);
            pd[j] += __shfl_xor(pd[j], off, 64);
        }
    }
    if ((cg & 7) == 0) {
#pragma unroll
        for (int j = 0; j < 4; ++j) {
            int row = r0 + rbase + j;
            if (row < n_nodes) {
                asrc[2 * row + head] = ps[j];
                adst[2 * row + head] = pd[j];
            }
        }
    }
}

// ---------------- merged CSR build (industry segs [0,N), universe [N,2N)) ----------------
__global__ void k_deg2(const int* __restrict__ ei_i, const int* __restrict__ ei_u,
                       int* __restrict__ deg, int ne) {
    int i = blockIdx.x * blockDim.x + threadIdx.x;
    if (i < ne) atomicAdd(&deg[ei_i[ne + i]], 1);
    else if (i < 2 * ne) atomicAdd(&deg[NNODES + ei_u[ne + (i - ne)]], 1);
}

__global__ void k_scan_block(const int* __restrict__ deg, int* __restrict__ offs,
                             int* __restrict__ bsums, int n) {
    __shared__ int sd[256];
    int t = threadIdx.x;
    int i = blockIdx.x * 256 + t;
    int v = (i < n) ? deg[i] : 0;
    sd[t] = v;
    __syncthreads();
    for (int off = 1; off < 256; off <<= 1) {
        int u = (t >= off) ? sd[t - off] : 0;
        __syncthreads();
        sd[t] += u;
        __syncthreads();
    }
    if (i < n) offs[i] = sd[t] - v;
    if (t == 255) bsums[blockIdx.x] = sd[255];
}

__global__ void k_scan_top(int* __restrict__ bsums, int nb) {   // <<<1,512>>>
    __shared__ int sd[512];
    int t = threadIdx.x;
    int v = (t < nb) ? bsums[t] : 0;
    sd[t] = v;
    __syncthreads();
    for (int off = 1; off < 512; off <<= 1) {
        int u = (t >= off) ? sd[t - off] : 0;
        __syncthreads();
        sd[t] += u;
        __syncthreads();
    }
    if (t < nb) bsums[t] = sd[t] - v;
}

__global__ void k_scan_add(int* __restrict__ offs, const int* __restrict__ bsums,
                           int* __restrict__ cursor, int n, int ne) {
    int i = blockIdx.x * 256 + threadIdx.x;
    if (i < n) {
        int o = offs[i] + bsums[blockIdx.x];
        offs[i] = o;
        cursor[i] = o;
    }
    if (i == 0) offs[n] = ne;
}

__global__ void k_fill2(const int* __restrict__ ei_i, const int* __restrict__ ei_u,
                        int* __restrict__ cursor, int* __restrict__ ssrc, int ne) {
    int i = blockIdx.x * blockDim.x + threadIdx.x;
    if (i < ne) {
        int d = ei_i[ne + i];
        int p = atomicAdd(&cursor[d], 1);
        ssrc[p] = ei_i[i];
    } else if (i < 2 * ne) {
        int j = i - ne;
        int d = NNODES + ei_u[ne + j];
        int p = atomicAdd(&cursor[d], 1);
        ssrc[p] = ei_u[j];
    }
}

// ---------------- GAT aggregation: one wave per dst node, single pass (no max) ----------------
__launch_bounds__(256)
__global__ void k_gat_agg(const float* __restrict__ Cin, const float* __restrict__ xl,
                          const float* __restrict__ asrc, const float* __restrict__ adst,
                          const int* __restrict__ offs, const int* __restrict__ ssrc,
                          const float* __restrict__ bias, float* __restrict__ Cout,
                          int n_nodes) {
    int wid = (blockIdx.x * blockDim.x + threadIdx.x) >> 6;
    int lane = threadIdx.x & 63;
    if (wid >= n_nodes) return;
    int n = wid;
    int h = lane >> 5;
    int beg = offs[n], end = offs[n + 1];
    float adh = adst[2 * n + h];
    const float2* xl2 = (const float2*)xl;
    // self loop
    float ee = __expf(leakyf(asrc[2 * n + h] + adh));
    float2 v = xl2[(size_t)n * 64 + lane];
    float acc0 = ee * v.x, acc1 = ee * v.y, dn = ee;
    for (int i = beg; i < end; ++i) {
        int s = ssrc[i];
        float e2 = __expf(leakyf(asrc[2 * s + h] + adh));
        float2 u = xl2[(size_t)s * 64 + lane];
        acc0 += e2 * u.x; acc1 += e2 * u.y; dn += e2;
    }
    float inv = 1.0f / dn;
    float o0 = acc0 * inv, o1 = acc1 * inv;
    float p0 = __shfl_xor(o0, 32, 64);
    float p1 = __shfl_xor(o1, 32, 64);
    if (lane < 32) {
        int c0 = 2 * lane;
        float hv0 = eluf(0.5f * (o0 + p0) + bias[c0]);
        float hv1 = eluf(0.5f * (o1 + p1) + bias[c0 + 1]);
        float2 cv = *(const float2*)(Cin + (size_t)n * 64 + c0);
        *(float2*)(Cout + (size_t)n * 64 + c0) = make_float2(cv.x - hv0, cv.y - hv1);
    }
}

// ---------------- Decoder ----------------
__launch_bounds__(256, 3)
__global__ void k_dec(const float* __restrict__ Cenc, const float* __restrict__ CI,
                      const float* __restrict__ CU, const float* __restrict__ w1,
                      const float* __restrict__ b1, const float* __restrict__ w2,
                      const float* __restrict__ b2, float* __restrict__ out, int n_nodes) {
    __shared__ float Fs[64][193];
    int t = threadIdx.x;
    int r0 = blockIdx.x * 64;
    const float* srcs[3] = {Cenc, CI, CU};
#pragma unroll
    for (int s = 0; s < 3; ++s) {
        const float* src = srcs[s];
#pragma unroll
        for (int it = 0; it < 4; ++it) {
            int idx = it * 256 + t;
            int row = idx >> 4;
            int col = (idx & 15) * 4;
            float4 v = make_float4(0.f, 0.f, 0.f, 0.f);
            if (r0 + row < n_nodes) v = *(const float4*)(src + (size_t)(r0 + row) * 64 + col);
            Fs[row][s * 64 + col + 0] = v.x; Fs[row][s * 64 + col + 1] = v.y;
            Fs[row][s * 64 + col + 2] = v.z; Fs[row][s * 64 + col + 3] = v.w;
        }
    }
    __syncthreads();
    int cg = t & 7, rs = t >> 3;
    int c0 = cg * 8, r2 = rs * 2;
    float acc[2][8];
    {
        float4 ba = *(const float4*)(b1 + c0);
        float4 bb = *(const float4*)(b1 + c0 + 4);
#pragma unroll
        for (int j = 0; j < 2; ++j) {
            acc[j][0] = ba.x; acc[j][1] = ba.y; acc[j][2] = ba.z; acc[j][3] = ba.w;
            acc[j][4] = bb.x; acc[j][5] = bb.y; acc[j][6] = bb.z; acc[j][7] = bb.w;
        }
    }
    {
        float4 wA[4], wB[4];
#pragma unroll
        for (int d = 0; d < 4; ++d) {
            wA[d] = *(const float4*)(w1 + d * 64 + c0);
            wB[d] = *(const float4*)(w1 + d * 64 + c0 + 4);
        }
        for (int k = 0; k < 192; k += 4) {
#pragma unroll
            for (int d = 0; d < 4; ++d) {
                int kn = k + 4 + d; if (kn > 191) kn = 191;
                float4 na = *(const float4*)(w1 + kn * 64 + c0);
                float4 nb = *(const float4*)(w1 + kn * 64 + c0 + 4);
                float f0 = Fs[r2 + 0][k + d];
                float f1 = Fs[r2 + 1][k + d];
                FMA8(acc[0], f0, wA[d], wB[d])
                FMA8(acc[1], f1, wA[d], wB[d])
                wA[d] = na; wB[d] = nb;
            }
        }
    }
    float4 w2a = *(const float4*)(w2 + c0);
    float4 w2b = *(const float4*)(w2 + c0 + 4);
    float b2v = b2[0];
#pragma unroll
    for (int j = 0; j < 2; ++j) {
        float p = leakyf(acc[j][0])*w2a.x + leakyf(acc[j][1])*w2a.y
                + leakyf(acc[j][2])*w2a.z + leakyf(acc[j][3])*w2a.w
                + leakyf(acc[j][4])*w2b.x + leakyf(acc[j][5])*w2b.y
                + leakyf(acc[j][6])*w2b.z + leakyf(acc[j][7])*w2b.w;
#pragma unroll
        for (int off = 1; off < 8; off <<= 1) p += __shfl_xor(p, off, 64);
        int row = r0 + r2 + j;
        if (cg == 0 && row < n_nodes) out[row] = p + b2v;
    }
}

// ---------------- Factor attention ----------------
__launch_bounds__(256, 4)
__global__ void k_fa(const float* __restrict__ x, const float* __restrict__ w,
                     const float* __restrict__ b, float* __restrict__ attn, int n_nodes) {
    __shared__ float Xs[64][133];
    int t = threadIdx.x;
    int r0 = blockIdx.x * 64;
#pragma unroll
    for (int it = 0; it < 8; ++it) {
        int idx = it * 256 + t;
        int row = idx >> 5;
        int col = (idx & 31) * 4;
        float4 v = make_float4(0.f, 0.f, 0.f, 0.f);
        if (r0 + row < n_nodes) v = *(const float4*)(x + (size_t)(r0 + row) * 128 + col);
        Xs[row][col + 0] = v.x; Xs[row][col + 1] = v.y;
        Xs[row][col + 2] = v.z; Xs[row][col + 3] = v.w;
    }
    __syncthreads();
    int cg = t & 15, rsub = t >> 4;
    int c0 = cg * 8, rbase = rsub * 4;
    float acc[4][8];
    {
        float4 ba = *(const float4*)(b + c0);
        float4 bb = *(const float4*)(b + c0 + 4);
#pragma unroll
        for (int j = 0; j < 4; ++j) {
            acc[j][0] = ba.x; acc[j][1] = ba.y; acc[j][2] = ba.z; acc[j][3] = ba.w;
            acc[j][4] = bb.x; acc[j][5] = bb.y; acc[j][6] = bb.z; acc[j][7] = bb.w;
        }
    }
    {
        float4 wA[4], wB[4];
#pragma unroll
        for (int d = 0; d < 4; ++d) {
            wA[d] = *(const float4*)(w + d * 128 + c0);
            wB[d] = *(const float4*)(w + d * 128 + c0 + 4);
        }
        for (int k = 0; k < 128; k += 4) {
#pragma unroll
            for (int d = 0; d < 4; ++d) {
                int kn = (k + 4 + d) & 127;
                float4 na = *(const float4*)(w + kn * 128 + c0);
                float4 nb = *(const float4*)(w + kn * 128 + c0 + 4);
                float x0 = Xs[rbase + 0][k + d];
                float x1 = Xs[rbase + 1][k + d];
                float x2 = Xs[rbase + 2][k + d];
                float x3 = Xs[rbase + 3][k + d];
                FMA8(acc[0], x0, wA[d], wB[d])
                FMA8(acc[1], x1, wA[d], wB[d])
                FMA8(acc[2], x2, wA[d], wB[d])
                FMA8(acc[3], x3, wA[d], wB[d])
                wA[d] = na; wB[d] = nb;
            }
        }
    }
    // per-row softmax over 128 cols: 16 cg-lanes cooperate
#pragma unroll
    for (int j = 0; j < 4; ++j) {
        float m = -1e30f;
#pragma unroll
        for (int i = 0; i < 8; ++i) {
            acc[j][i] = leakyf(acc[j][i]);
            m = fmaxf(m, acc[j][i]);
        }
#pragma unroll
        for (int off = 1; off < 16; off <<= 1) m = fmaxf(m, __shfl_xor(m, off, 64));
        float s = 0.f;
#pragma unroll
        for (int i = 0; i < 8; ++i) {
            acc[j][i] = __expf(acc[j][i] - m);
            s += acc[j][i];
        }
#pragma unroll
        for (int off = 1; off < 16; off <<= 1) s += __shfl_xor(s, off, 64);
        float inv = 1.0f / s;
        int row = r0 + rbase + j;
        if (row < n_nodes) {
            float* o = attn + (size_t)row * 128 + c0;
            *(float4*)o       = make_float4(acc[j][0]*inv, acc[j][1]*inv, acc[j][2]*inv, acc[j][3]*inv);
            *(float4*)(o + 4) = make_float4(acc[j][4]*inv, acc[j][5]*inv, acc[j][6]*inv, acc[j][7]*inv);
        }
    }
}

extern "C" void kernel_launch(void* const* d_in, const int* in_sizes, int n_in,
                              void* d_out, int out_size, void* d_ws, size_t ws_size,
                              hipStream_t stream) {
    const float* x        = (const float*)d_in[0];
    const int*   ei_ind   = (const int*)d_in[1];
    const int*   ei_uni   = (const int*)d_in[2];
    const float* bn_gamma = (const float*)d_in[3];
    const float* bn_beta  = (const float*)d_in[4];
    const float* enc_w1   = (const float*)d_in[5];
    const float* enc_b1   = (const float*)d_in[6];
    const float* enc_w2   = (const float*)d_in[7];
    const float* enc_b2   = (const float*)d_in[8];
    const float* gi_w     = (const float*)d_in[9];
    const float* gi_as    = (const float*)d_in[10];
    const float* gi_ad    = (const float*)d_in[11];
    const float* gi_b     = (const float*)d_in[12];
    const float* gu_w     = (const float*)d_in[13];
    const float* gu_as    = (const float*)d_in[14];
    const float* gu_ad    = (const float*)d_in[15];
    const float* gu_b     = (const float*)d_in[16];
    const float* dec_w1   = (const float*)d_in[17];
    const float* dec_b1   = (const float*)d_in[18];
    const float* dec_w2   = (const float*)d_in[19];
    const float* dec_b2   = (const float*)d_in[20];
    const float* fa_w     = (const float*)d_in[21];
    const float* fa_b     = (const float*)d_in[22];

    const int N = NNODES, E = NEDGES;

    float* Cenc  = (float*)d_ws;
    float* C_I   = Cenc + (size_t)N * 64;
    float* C_U   = C_I + (size_t)N * 64;
    float* xl    = C_U + (size_t)N * 64;
    float* a_src = xl + (size_t)N * 128;
    float* a_dst = a_src + (size_t)N * 2;
    float* bnacc = a_dst + (size_t)N * 2;
    float* bnss  = bnacc + 256;
    int* deg2    = (int*)(bnss + 256);
    int* offs2   = deg2 + N2;
    int* cursor2 = offs2 + N2 + 1;
    int* bsums2  = cursor2 + N2;
    int* ssrc2   = bsums2 + 512;

    float* out_deep = (float*)d_out;
    float* out_attn = out_deep + N;

    // ---- BatchNorm stats ----
    hipMemsetAsync(bnacc, 0, 256 * sizeof(float), stream);
    k_bn_stats<<<256, 256, 0, stream>>>(x, bnacc, N);
    k_bn_final<<<1, 128, 0, stream>>>(bnacc, bn_gamma, bn_beta, bnss, N);

    // ---- Encoder ----
    k_encoder<<<NBLK64, 256, 0, stream>>>(x, bnss, enc_w1, enc_b1, enc_w2, enc_b2, Cenc, N);

    // ---- merged CSR build for both graphs ----
    hipMemsetAsync(deg2, 0, N2 * sizeof(int), stream);
    k_deg2<<<(2 * E + 255) / 256, 256, 0, stream>>>(ei_ind, ei_uni, deg2, E);
    k_scan_block<<<NB2_SCAN, 256, 0, stream>>>(deg2, offs2, bsums2, N2);
    k_scan_top<<<1, 512, 0, stream>>>(bsums2, NB2_SCAN);
    k_scan_add<<<NB2_SCAN, 256, 0, stream>>>(offs2, bsums2, cursor2, N2, 2 * E);
    k_fill2<<<(2 * E + 255) / 256, 256, 0, stream>>>(ei_ind, ei_uni, cursor2, ssrc2, E);

    // ---- Industry GAT ----
    k_xl<<<NBLK64, 256, 0, stream>>>(Cenc, gi_w, gi_as, gi_ad, xl, a_src, a_dst, N);
    k_gat_agg<<<(N + 3) / 4, 256, 0, stream>>>(Cenc, xl, a_src, a_dst, offs2, ssrc2, gi_b, C_I, N);

    // ---- Universe GAT ----
    k_xl<<<NBLK64, 256, 0, stream>>>(C_I, gu_w, gu_as, gu_ad, xl, a_src, a_dst, N);
    k_gat_agg<<<(N + 3) / 4, 256, 0, stream>>>(C_I, xl, a_src, a_dst, offs2 + N, ssrc2, gu_b, C_U, N);

    // ---- Decoder + factor attention ----
    k_dec<<<NBLK64, 256, 0, stream>>>(Cenc, C_I, C_U, dec_w1, dec_b1, dec_w2, dec_b2, out_deep, N);
    k_fa<<<NBLK64, 256, 0, stream>>>(x, fa_w, fa_b, out_attn, N);
}

// Round 4
// 628.481 us; speedup vs baseline: 2.7539x; 1.2360x over previous
//
#include <hip/hip_runtime.h>
#include <hip/hip_bf16.h>
#include <math.h>

#define NNODES 50000
#define FDIM   128
#define HIDDIM 64
#define NEDGES 800000
#define NBLK64 782          // ceil(50000/64)
#define N2     (2*NNODES)
#define NB_A   256
#define CHUNK  6250         // 2*NEDGES / NB_A (exact)
#define NBUCK  391          // ceil(100000/256)
#define NBPAD  512

__device__ __forceinline__ float leakyf(float x) { return x > 0.f ? x : 0.2f * x; }
__device__ __forceinline__ float eluf(float x)   { return x > 0.f ? x : expm1f(x); }

#define FMA8(A, xv, wa, wb) \
    A[0] += xv * wa.x; A[1] += xv * wa.y; A[2] += xv * wa.z; A[3] += xv * wa.w; \
    A[4] += xv * wb.x; A[5] += xv * wb.y; A[6] += xv * wb.z; A[7] += xv * wb.w;

// ---------------- BatchNorm statistics ----------------
__global__ void k_bn_stats(const float* __restrict__ x, float* __restrict__ acc, int n) {
    int t = threadIdx.x;
    int f = t & 127, half = t >> 7;
    int rows_per_block = (n + gridDim.x - 1) / gridDim.x;
    int r0 = blockIdx.x * rows_per_block;
    int r1 = min(r0 + rows_per_block, n);
    float s = 0.f, s2 = 0.f;
    for (int r = r0 + half; r < r1; r += 2) {
        float v = x[(size_t)r * 128 + f];
        s += v; s2 += v * v;
    }
    __shared__ float ls[256], ls2[256];
    ls[t] = s; ls2[t] = s2;
    __syncthreads();
    if (t < 128) {
        s  = ls[t]  + ls[t + 128];
        s2 = ls2[t] + ls2[t + 128];
        atomicAdd(&acc[f], s);
        atomicAdd(&acc[128 + f], s2);
    }
}

__global__ void k_bn_final(const float* __restrict__ acc, const float* __restrict__ gamma,
                           const float* __restrict__ beta, float* __restrict__ ss, int n) {
    int f = threadIdx.x;
    if (f < 128) {
        float inv_n = 1.0f / (float)n;
        float mean = acc[f] * inv_n;
        float var  = acc[128 + f] * inv_n - mean * mean;
        float sc = gamma[f] * rsqrtf(var + 1e-5f);
        ss[f] = sc;
        ss[128 + f] = beta[f] - mean * sc;
    }
}

// ---------------- Fused BN + encoder, 64-row tile, prefetched weights ----------------
__launch_bounds__(256, 4)
__global__ void k_encoder(const float* __restrict__ x, const float* __restrict__ bnss,
                          const float* __restrict__ w1, const float* __restrict__ b1,
                          const float* __restrict__ w2, const float* __restrict__ b2,
                          float* __restrict__ Cenc, int n_nodes) {
    __shared__ float Xs[64][133];
    int t = threadIdx.x;
    int r0 = blockIdx.x * 64;
#pragma unroll
    for (int it = 0; it < 8; ++it) {
        int idx = it * 256 + t;
        int row = idx >> 5;
        int col = (idx & 31) * 4;
        float4 v = make_float4(0.f, 0.f, 0.f, 0.f);
        if (r0 + row < n_nodes) v = *(const float4*)(x + (size_t)(r0 + row) * 128 + col);
        float4 sc = *(const float4*)(bnss + col);
        float4 sh = *(const float4*)(bnss + 128 + col);
        Xs[row][col + 0] = v.x * sc.x + sh.x;
        Xs[row][col + 1] = v.y * sc.y + sh.y;
        Xs[row][col + 2] = v.z * sc.z + sh.z;
        Xs[row][col + 3] = v.w * sc.w + sh.w;
    }
    __syncthreads();
    int cg = t & 15, rsub = t >> 4;
    int c0 = cg * 8, rbase = rsub * 4;
    float acc[4][8];
    {
        float4 ba = *(const float4*)(b1 + c0);
        float4 bb = *(const float4*)(b1 + c0 + 4);
#pragma unroll
        for (int j = 0; j < 4; ++j) {
            acc[j][0] = ba.x; acc[j][1] = ba.y; acc[j][2] = ba.z; acc[j][3] = ba.w;
            acc[j][4] = bb.x; acc[j][5] = bb.y; acc[j][6] = bb.z; acc[j][7] = bb.w;
        }
    }
    {
        float4 wA[4], wB[4];
#pragma unroll
        for (int d = 0; d < 4; ++d) {
            wA[d] = *(const float4*)(w1 + d * 128 + c0);
            wB[d] = *(const float4*)(w1 + d * 128 + c0 + 4);
        }
        for (int k = 0; k < 128; k += 4) {
#pragma unroll
            for (int d = 0; d < 4; ++d) {
                int kn = (k + 4 + d) & 127;
                float4 na = *(const float4*)(w1 + kn * 128 + c0);
                float4 nb = *(const float4*)(w1 + kn * 128 + c0 + 4);
                float x0 = Xs[rbase + 0][k + d];
                float x1 = Xs[rbase + 1][k + d];
                float x2 = Xs[rbase + 2][k + d];
                float x3 = Xs[rbase + 3][k + d];
                FMA8(acc[0], x0, wA[d], wB[d])
                FMA8(acc[1], x1, wA[d], wB[d])
                FMA8(acc[2], x2, wA[d], wB[d])
                FMA8(acc[3], x3, wA[d], wB[d])
                wA[d] = na; wB[d] = nb;
            }
        }
    }
    __syncthreads();
#pragma unroll
    for (int j = 0; j < 4; ++j)
#pragma unroll
        for (int i = 0; i < 8; ++i)
            Xs[rbase + j][c0 + i] = fmaxf(acc[j][i], 0.f);
    __syncthreads();
    int cg2 = t & 7, rs2 = t >> 3;
    int c2 = cg2 * 8, r2 = rs2 * 2;
    float a2[2][8];
    {
        float4 ba = *(const float4*)(b2 + c2);
        float4 bb = *(const float4*)(b2 + c2 + 4);
#pragma unroll
        for (int j = 0; j < 2; ++j) {
            a2[j][0] = ba.x; a2[j][1] = ba.y; a2[j][2] = ba.z; a2[j][3] = ba.w;
            a2[j][4] = bb.x; a2[j][5] = bb.y; a2[j][6] = bb.z; a2[j][7] = bb.w;
        }
    }
    {
        float4 wA[4], wB[4];
#pragma unroll
        for (int d = 0; d < 4; ++d) {
            wA[d] = *(const float4*)(w2 + d * 64 + c2);
            wB[d] = *(const float4*)(w2 + d * 64 + c2 + 4);
        }
        for (int k = 0; k < 128; k += 4) {
#pragma unroll
            for (int d = 0; d < 4; ++d) {
                int kn = (k + 4 + d) & 127;
                float4 na = *(const float4*)(w2 + kn * 64 + c2);
                float4 nb = *(const float4*)(w2 + kn * 64 + c2 + 4);
                float h0 = Xs[r2 + 0][k + d];
                float h1 = Xs[r2 + 1][k + d];
                FMA8(a2[0], h0, wA[d], wB[d])
                FMA8(a2[1], h1, wA[d], wB[d])
                wA[d] = na; wB[d] = nb;
            }
        }
    }
#pragma unroll
    for (int j = 0; j < 2; ++j) {
        int row = r0 + r2 + j;
        if (row < n_nodes) {
            float* o = Cenc + (size_t)row * 64 + c2;
            *(float4*)o       = make_float4(fmaxf(a2[j][0], 0.f), fmaxf(a2[j][1], 0.f),
                                            fmaxf(a2[j][2], 0.f), fmaxf(a2[j][3], 0.f));
            *(float4*)(o + 4) = make_float4(fmaxf(a2[j][4], 0.f), fmaxf(a2[j][5], 0.f),
                                            fmaxf(a2[j][6], 0.f), fmaxf(a2[j][7], 0.f));
        }
    }
}

// ---------------- GAT: xl = Cin @ W + fused attention logits ----------------
__launch_bounds__(256, 4)
__global__ void k_xl(const float* __restrict__ Cin, const float* __restrict__ Wg,
                     const float* __restrict__ attS, const float* __restrict__ attD,
                     float* __restrict__ xl, float* __restrict__ asrc, float* __restrict__ adst,
                     int n_nodes) {
    __shared__ float Cs[64][65];
    int t = threadIdx.x;
    int r0 = blockIdx.x * 64;
#pragma unroll
    for (int it = 0; it < 4; ++it) {
        int idx = it * 256 + t;
        int row = idx >> 4;
        int col = (idx & 15) * 4;
        float4 v = make_float4(0.f, 0.f, 0.f, 0.f);
        if (r0 + row < n_nodes) v = *(const float4*)(Cin + (size_t)(r0 + row) * 64 + col);
        Cs[row][col + 0] = v.x; Cs[row][col + 1] = v.y;
        Cs[row][col + 2] = v.z; Cs[row][col + 3] = v.w;
    }
    __syncthreads();
    int cg = t & 15, rsub = t >> 4;
    int c0 = cg * 8, rbase = rsub * 4;
    float acc[4][8];
#pragma unroll
    for (int j = 0; j < 4; ++j)
#pragma unroll
        for (int i = 0; i < 8; ++i) acc[j][i] = 0.f;
    {
        float4 wA[4], wB[4];
#pragma unroll
        for (int d = 0; d < 4; ++d) {
            wA[d] = *(const float4*)(Wg + d * 128 + c0);
            wB[d] = *(const float4*)(Wg + d * 128 + c0 + 4);
        }
        for (int k = 0; k < 64; k += 4) {
#pragma unroll
            for (int d = 0; d < 4; ++d) {
                int kn = (k + 4 + d) & 63;
                float4 na = *(const float4*)(Wg + kn * 128 + c0);
                float4 nb = *(const float4*)(Wg + kn * 128 + c0 + 4);
                float x0 = Cs[rbase + 0][k + d];
                float x1 = Cs[rbase + 1][k + d];
                float x2 = Cs[rbase + 2][k + d];
                float x3 = Cs[rbase + 3][k + d];
                FMA8(acc[0], x0, wA[d], wB[d])
                FMA8(acc[1], x1, wA[d], wB[d])
                FMA8(acc[2], x2, wA[d], wB[d])
                FMA8(acc[3], x3, wA[d], wB[d])
                wA[d] = na; wB[d] = nb;
            }
        }
    }
#pragma unroll
    for (int j = 0; j < 4; ++j) {
        int row = r0 + rbase + j;
        if (row < n_nodes) {
            float* o = xl + (size_t)row * 128 + c0;
            *(float4*)o       = make_float4(acc[j][0], acc[j][1], acc[j][2], acc[j][3]);
            *(float4*)(o + 4) = make_float4(acc[j][4], acc[j][5], acc[j][6], acc[j][7]);
        }
    }
    int head = cg >> 3;
    const float* as_ = attS + head * 64 + (cg & 7) * 8;
    const float* ad_ = attD + head * 64 + (cg & 7) * 8;
    float4 sa = *(const float4*)as_,       sb = *(const float4*)(as_ + 4);
    float4 da = *(const float4*)ad_,       db = *(const float4*)(ad_ + 4);
    float ps[4], pd[4];
#pragma unroll
    for (int j = 0; j < 4; ++j) {
        ps[j] = acc[j][0]*sa.x + acc[j][1]*sa.y + acc[j][2]*sa.z + acc[j][3]*sa.w
              + acc[j][4]*sb.x + acc[j][5]*sb.y + acc[j][6]*sb.z + acc[j][7]*sb.w;
        pd[j] = acc[j][0]*da.x + acc[j][1]*da.y + acc[j][2]*da.z + acc[j][3]*da.w
              + acc[j][4]*db.x + acc[j][5]*db.y + acc[j][6]*db.z + acc[j][7]*db.w;
#pragma unroll
        for (int off = 1; off < 8; off <<= 1) {
            ps[j] += __shfl_xor(ps[j], off, 64);
            pd[j] += __shfl_xor(pd[j], off, 64);
        }
    }
    if ((cg & 7) == 0) {
#pragma unroll
        for (int j = 0; j < 4; ++j) {
            int row = r0 + rbase + j;
            if (row < n_nodes) {
                asrc[2 * row + head] = ps[j];
                adst[2 * row + head] = pd[j];
            }
        }
    }
}

// ================ CSR build via two-level counting sort ================
// A1: per-chunk bucket histogram (bucket = dst2 >> 8)
__launch_bounds__(256)
__global__ void k_hist(const int* __restrict__ ei_i, const int* __restrict__ ei_u,
                       int* __restrict__ counts) {
    __shared__ int hist[NBPAD];
    int t = threadIdx.x, blk = blockIdx.x;
    for (int i = t; i < NBPAD; i += 256) hist[i] = 0;
    __syncthreads();
    int p0 = blk * CHUNK;
    for (int k = 0; k < CHUNK; k += 256) {
        if (k + t < CHUNK) {
            int p = p0 + k + t;
            int d2 = (p < NEDGES) ? ei_i[NEDGES + p]
                                  : (NNODES + ei_u[NEDGES + (p - NEDGES)]);
            atomicAdd(&hist[d2 >> 8], 1);
        }
    }
    __syncthreads();
    for (int i = t; i < NBPAD; i += 256) counts[blk * NBPAD + i] = hist[i];  // [blk][bucket]
}

// A2a: per-bucket exclusive scan over blocks
__launch_bounds__(256)
__global__ void k_rowscan(const int* __restrict__ counts, int* __restrict__ offsets,
                          int* __restrict__ totals) {
    __shared__ int sd[256];
    int b = blockIdx.x;   // bucket
    int t = threadIdx.x;  // chunk-block index
    int v = counts[t * NBPAD + b];
    sd[t] = v;
    __syncthreads();
    for (int off = 1; off < 256; off <<= 1) {
        int u = (t >= off) ? sd[t - off] : 0;
        __syncthreads();
        sd[t] += u;
        __syncthreads();
    }
    offsets[t * NBPAD + b] = sd[t] - v;
    if (t == 255) totals[b] = sd[255];
}

// A2b: exclusive scan of bucket totals
__launch_bounds__(512)
__global__ void k_bscan(const int* __restrict__ totals, int* __restrict__ bucketBase) {
    __shared__ int sd[512];
    int t = threadIdx.x;
    int v = totals[t];
    sd[t] = v; __syncthreads();
    for (int off = 1; off < 512; off <<= 1) {
        int u = (t >= off) ? sd[t - off] : 0;
        __syncthreads();
        sd[t] += u;
        __syncthreads();
    }
    bucketBase[t] = sd[t] - v;
    if (t == 511) bucketBase[512] = sd[511];
}

// A3: LDS counting-sort per chunk, burst-write bucket-major staging
__launch_bounds__(256, 2)
__global__ void k_stage(const int* __restrict__ ei_i, const int* __restrict__ ei_u,
                        const int* __restrict__ offsets, const int* __restrict__ bucketBase,
                        unsigned int* __restrict__ staging) {
    __shared__ int hist[NBPAD];
    __shared__ int runstart[NBPAD];
    __shared__ int cursor[NBPAD];
    __shared__ int delta[NBPAD];
    __shared__ int sd[256];
    __shared__ unsigned int sorted[CHUNK];
    __shared__ unsigned short slotb[CHUNK];
    int t = threadIdx.x, blk = blockIdx.x;
    for (int i = t; i < NBPAD; i += 256) hist[i] = 0;
    __syncthreads();
    int p0 = blk * CHUNK;
    for (int k = 0; k < CHUNK; k += 256) {
        if (k + t < CHUNK) {
            int p = p0 + k + t;
            int d2 = (p < NEDGES) ? ei_i[NEDGES + p]
                                  : (NNODES + ei_u[NEDGES + (p - NEDGES)]);
            atomicAdd(&hist[d2 >> 8], 1);
        }
    }
    __syncthreads();
    // scan 512 bins with 256 threads (2 per thread)
    int v0 = hist[2 * t], v1 = hist[2 * t + 1];
    int s = v0 + v1;
    sd[t] = s; __syncthreads();
    for (int off = 1; off < 256; off <<= 1) {
        int u = (t >= off) ? sd[t - off] : 0;
        __syncthreads();
        sd[t] += u;
        __syncthreads();
    }
    int base = sd[t] - s;
    runstart[2 * t] = base;
    runstart[2 * t + 1] = base + v0;
    __syncthreads();
    for (int i = t; i < NBPAD; i += 256) {
        cursor[i] = runstart[i];
        delta[i] = bucketBase[i] + offsets[blk * NBPAD + i] - runstart[i];
    }
    __syncthreads();
    for (int k = 0; k < CHUNK; k += 256) {
        if (k + t < CHUNK) {
            int p = p0 + k + t;
            int src, d2;
            if (p < NEDGES) { src = ei_i[p]; d2 = ei_i[NEDGES + p]; }
            else { int q = p - NEDGES; src = ei_u[q]; d2 = NNODES + ei_u[NEDGES + q]; }
            int b = d2 >> 8;
            int pos = atomicAdd(&cursor[b], 1);
            sorted[pos] = ((unsigned)src << 8) | (unsigned)(d2 & 255);
            slotb[pos] = (unsigned short)b;
        }
    }
    __syncthreads();
    for (int k = t; k < CHUNK; k += 256) {
        int b = slotb[k];
        staging[delta[b] + k] = sorted[k];
    }
}

// B: per-bucket bin sort -> ssrc (coalesced in L2) + per-node CSR offsets
__launch_bounds__(256)
__global__ void k_binsort(const unsigned int* __restrict__ staging,
                          const int* __restrict__ bucketBase,
                          int* __restrict__ ssrc, int* __restrict__ offs2) {
    __shared__ int hist[256];
    __shared__ int cursor[256];
    __shared__ int sd[256];
    int b = blockIdx.x, t = threadIdx.x;
    int base = bucketBase[b];
    int cnt  = bucketBase[b + 1] - base;
    hist[t] = 0;
    __syncthreads();
    for (int p = t; p < cnt; p += 256)
        atomicAdd(&hist[staging[base + p] & 255u], 1);
    __syncthreads();
    int v = hist[t];
    sd[t] = v; __syncthreads();
    for (int off = 1; off < 256; off <<= 1) {
        int u = (t >= off) ? sd[t - off] : 0;
        __syncthreads();
        sd[t] += u;
        __syncthreads();
    }
    int excl = sd[t] - v;
    cursor[t] = excl;
    int d2 = b * 256 + t;
    if (d2 <= N2) offs2[d2] = base + excl;
    __syncthreads();
    for (int p = t; p < cnt; p += 256) {
        unsigned int e = staging[base + p];
        int pos = atomicAdd(&cursor[e & 255u], 1);
        ssrc[base + pos] = (int)(e >> 8);
    }
}

// ---------------- GAT aggregation: one wave per dst node, single pass ----------------
__launch_bounds__(256)
__global__ void k_gat_agg(const float* __restrict__ Cin, const float* __restrict__ xl,
                          const float* __restrict__ asrc, const float* __restrict__ adst,
                          const int* __restrict__ offs, const int* __restrict__ ssrc,
                          const float* __restrict__ bias, float* __restrict__ Cout,
                          int n_nodes) {
    int wid = (blockIdx.x * blockDim.x + threadIdx.x) >> 6;
    int lane = threadIdx.x & 63;
    if (wid >= n_nodes) return;
    int n = wid;
    int h = lane >> 5;
    int beg = offs[n], end = offs[n + 1];
    float adh = adst[2 * n + h];
    const float2* xl2 = (const float2*)xl;
    float ee = __expf(leakyf(asrc[2 * n + h] + adh));
    float2 v = xl2[(size_t)n * 64 + lane];
    float acc0 = ee * v.x, acc1 = ee * v.y, dn = ee;
    for (int i = beg; i < end; ++i) {
        int s = ssrc[i];
        float e2 = __expf(leakyf(asrc[2 * s + h] + adh));
        float2 u = xl2[(size_t)s * 64 + lane];
        acc0 += e2 * u.x; acc1 += e2 * u.y; dn += e2;
    }
    float inv = 1.0f / dn;
    float o0 = acc0 * inv, o1 = acc1 * inv;
    float p0 = __shfl_xor(o0, 32, 64);
    float p1 = __shfl_xor(o1, 32, 64);
    if (lane < 32) {
        int c0 = 2 * lane;
        float hv0 = eluf(0.5f * (o0 + p0) + bias[c0]);
        float hv1 = eluf(0.5f * (o1 + p1) + bias[c0 + 1]);
        float2 cv = *(const float2*)(Cin + (size_t)n * 64 + c0);
        *(float2*)(Cout + (size_t)n * 64 + c0) = make_float2(cv.x - hv0, cv.y - hv1);
    }
}

// ---------------- Decoder ----------------
__launch_bounds__(256, 3)
__global__ void k_dec(const float* __restrict__ Cenc, const float* __restrict__ CI,
                      const float* __restrict__ CU, const float* __restrict__ w1,
                      const float* __restrict__ b1, const float* __restrict__ w2,
                      const float* __restrict__ b2, float* __restrict__ out, int n_nodes) {
    __shared__ float Fs[64][193];
    int t = threadIdx.x;
    int r0 = blockIdx.x * 64;
    const float* srcs[3] = {Cenc, CI, CU};
#pragma unroll
    for (int s = 0; s < 3; ++s) {
        const float* src = srcs[s];
#pragma unroll
        for (int it = 0; it < 4; ++it) {
            int idx = it * 256 + t;
            int row = idx >> 4;
            int col = (idx & 15) * 4;
            float4 v = make_float4(0.f, 0.f, 0.f, 0.f);
            if (r0 + row < n_nodes) v = *(const float4*)(src + (size_t)(r0 + row) * 64 + col);
            Fs[row][s * 64 + col + 0] = v.x; Fs[row][s * 64 + col + 1] = v.y;
            Fs[row][s * 64 + col + 2] = v.z; Fs[row][s * 64 + col + 3] = v.w;
        }
    }
    __syncthreads();
    int cg = t & 7, rs = t >> 3;
    int c0 = cg * 8, r2 = rs * 2;
    float acc[2][8];
    {
        float4 ba = *(const float4*)(b1 + c0);
        float4 bb = *(const float4*)(b1 + c0 + 4);
#pragma unroll
        for (int j = 0; j < 2; ++j) {
            acc[j][0] = ba.x; acc[j][1] = ba.y; acc[j][2] = ba.z; acc[j][3] = ba.w;
            acc[j][4] = bb.x; acc[j][5] = bb.y; acc[j][6] = bb.z; acc[j][7] = bb.w;
        }
    }
    {
        float4 wA[4], wB[4];
#pragma unroll
        for (int d = 0; d < 4; ++d) {
            wA[d] = *(const float4*)(w1 + d * 64 + c0);
            wB[d] = *(const float4*)(w1 + d * 64 + c0 + 4);
        }
        for (int k = 0; k < 192; k += 4) {
#pragma unroll
            for (int d = 0; d < 4; ++d) {
                int kn = k + 4 + d; if (kn > 191) kn = 191;
                float4 na = *(const float4*)(w1 + kn * 64 + c0);
                float4 nb = *(const float4*)(w1 + kn * 64 + c0 + 4);
                float f0 = Fs[r2 + 0][k + d];
                float f1 = Fs[r2 + 1][k + d];
                FMA8(acc[0], f0, wA[d], wB[d])
                FMA8(acc[1], f1, wA[d], wB[d])
                wA[d] = na; wB[d] = nb;
            }
        }
    }
    float4 w2a = *(const float4*)(w2 + c0);
    float4 w2b = *(const float4*)(w2 + c0 + 4);
    float b2v = b2[0];
#pragma unroll
    for (int j = 0; j < 2; ++j) {
        float p = leakyf(acc[j][0])*w2a.x + leakyf(acc[j][1])*w2a.y
                + leakyf(acc[j][2])*w2a.z + leakyf(acc[j][3])*w2a.w
                + leakyf(acc[j][4])*w2b.x + leakyf(acc[j][5])*w2b.y
                + leakyf(acc[j][6])*w2b.z + leakyf(acc[j][7])*w2b.w;
#pragma unroll
        for (int off = 1; off < 8; off <<= 1) p += __shfl_xor(p, off, 64);
        int row = r0 + r2 + j;
        if (cg == 0 && row < n_nodes) out[row] = p + b2v;
    }
}

// ---------------- Factor attention ----------------
__launch_bounds__(256, 4)
__global__ void k_fa(const float* __restrict__ x, const float* __restrict__ w,
                     const float* __restrict__ b, float* __restrict__ attn, int n_nodes) {
    __shared__ float Xs[64][133];
    int t = threadIdx.x;
    int r0 = blockIdx.x * 64;
#pragma unroll
    for (int it = 0; it < 8; ++it) {
        int idx = it * 256 + t;
        int row = idx >> 5;
        int col = (idx & 31) * 4;
        float4 v = make_float4(0.f, 0.f, 0.f, 0.f);
        if (r0 + row < n_nodes) v = *(const float4*)(x + (size_t)(r0 + row) * 128 + col);
        Xs[row][col + 0] = v.x; Xs[row][col + 1] = v.y;
        Xs[row][col + 2] = v.z; Xs[row][col + 3] = v.w;
    }
    __syncthreads();
    int cg = t & 15, rsub = t >> 4;
    int c0 = cg * 8, rbase = rsub * 4;
    float acc[4][8];
    {
        float4 ba = *(const float4*)(b + c0);
        float4 bb = *(const float4*)(b + c0 + 4);
#pragma unroll
        for (int j = 0; j < 4; ++j) {
            acc[j][0] = ba.x; acc[j][1] = ba.y; acc[j][2] = ba.z; acc[j][3] = ba.w;
            acc[j][4] = bb.x; acc[j][5] = bb.y; acc[j][6] = bb.z; acc[j][7] = bb.w;
        }
    }
    {
        float4 wA[4], wB[4];
#pragma unroll
        for (int d = 0; d < 4; ++d) {
            wA[d] = *(const float4*)(w + d * 128 + c0);
            wB[d] = *(const float4*)(w + d * 128 + c0 + 4);
        }
        for (int k = 0; k < 128; k += 4) {
#pragma unroll
            for (int d = 0; d < 4; ++d) {
                int kn = (k + 4 + d) & 127;
                float4 na = *(const float4*)(w + kn * 128 + c0);
                float4 nb = *(const float4*)(w + kn * 128 + c0 + 4);
                float x0 = Xs[rbase + 0][k + d];
                float x1 = Xs[rbase + 1][k + d];
                float x2 = Xs[rbase + 2][k + d];
                float x3 = Xs[rbase + 3][k + d];
                FMA8(acc[0], x0, wA[d], wB[d])
                FMA8(acc[1], x1, wA[d], wB[d])
                FMA8(acc[2], x2, wA[d], wB[d])
                FMA8(acc[3], x3, wA[d], wB[d])
                wA[d] = na; wB[d] = nb;
            }
        }
    }
#pragma unroll
    for (int j = 0; j < 4; ++j) {
        float m = -1e30f;
#pragma unroll
        for (int i = 0; i < 8; ++i) {
            acc[j][i] = leakyf(acc[j][i]);
            m = fmaxf(m, acc[j][i]);
        }
#pragma unroll
        for (int off = 1; off < 16; off <<= 1) m = fmaxf(m, __shfl_xor(m, off, 64));
        float s = 0.f;
#pragma unroll
        for (int i = 0; i < 8; ++i) {
            acc[j][i] = __expf(acc[j][i] - m);
            s += acc[j][i];
        }
#pragma unroll
        for (int off = 1; off < 16; off <<= 1) s += __shfl_xor(s, off, 64);
        float inv = 1.0f / s;
        int row = r0 + rbase + j;
        if (row < n_nodes) {
            float* o = attn + (size_t)row * 128 + c0;
            *(float4*)o       = make_float4(acc[j][0]*inv, acc[j][1]*inv, acc[j][2]*inv, acc[j][3]*inv);
            *(float4*)(o + 4) = make_float4(acc[j][4]*inv, acc[j][5]*inv, acc[j][6]*inv, acc[j][7]*inv);
        }
    }
}

extern "C" void kernel_launch(void* const* d_in, const int* in_sizes, int n_in,
                              void* d_out, int out_size, void* d_ws, size_t ws_size,
                              hipStream_t stream) {
    const float* x        = (const float*)d_in[0];
    const int*   ei_ind   = (const int*)d_in[1];
    const int*   ei_uni   = (const int*)d_in[2];
    const float* bn_gamma = (const float*)d_in[3];
    const float* bn_beta  = (const float*)d_in[4];
    const float* enc_w1   = (const float*)d_in[5];
    const float* enc_b1   = (const float*)d_in[6];
    const float* enc_w2   = (const float*)d_in[7];
    const float* enc_b2   = (const float*)d_in[8];
    const float* gi_w     = (const float*)d_in[9];
    const float* gi_as    = (const float*)d_in[10];
    const float* gi_ad    = (const float*)d_in[11];
    const float* gi_b     = (const float*)d_in[12];
    const float* gu_w     = (const float*)d_in[13];
    const float* gu_as    = (const float*)d_in[14];
    const float* gu_ad    = (const float*)d_in[15];
    const float* gu_b     = (const float*)d_in[16];
    const float* dec_w1   = (const float*)d_in[17];
    const float* dec_b1   = (const float*)d_in[18];
    const float* dec_w2   = (const float*)d_in[19];
    const float* dec_b2   = (const float*)d_in[20];
    const float* fa_w     = (const float*)d_in[21];
    const float* fa_b     = (const float*)d_in[22];

    const int N = NNODES, E = NEDGES;

    float* Cenc  = (float*)d_ws;
    float* C_I   = Cenc + (size_t)N * 64;
    float* C_U   = C_I + (size_t)N * 64;
    float* xl    = C_U + (size_t)N * 64;
    float* a_src = xl + (size_t)N * 128;
    float* a_dst = a_src + (size_t)N * 2;
    float* bnacc = a_dst + (size_t)N * 2;
    float* bnss  = bnacc + 256;
    int* offs2      = (int*)(bnss + 256);
    int* ssrc2      = offs2 + (N2 + 1);
    int* counts     = ssrc2 + 2 * E;
    int* offsets    = counts + NB_A * NBPAD;
    int* totals     = offsets + NB_A * NBPAD;
    int* bucketBase = totals + NBPAD;          // 513 ints
    unsigned int* staging = (unsigned int*)xl; // aliases xl: CSR build finishes before k_xl

    float* out_deep = (float*)d_out;
    float* out_attn = out_deep + N;

    // ---- BatchNorm stats ----
    hipMemsetAsync(bnacc, 0, 256 * sizeof(float), stream);
    k_bn_stats<<<256, 256, 0, stream>>>(x, bnacc, N);
    k_bn_final<<<1, 128, 0, stream>>>(bnacc, bn_gamma, bn_beta, bnss, N);

    // ---- Encoder ----
    k_encoder<<<NBLK64, 256, 0, stream>>>(x, bnss, enc_w1, enc_b1, enc_w2, enc_b2, Cenc, N);

    // ---- CSR build (two-level counting sort, both graphs merged) ----
    k_hist<<<NB_A, 256, 0, stream>>>(ei_ind, ei_uni, counts);
    k_rowscan<<<NBPAD, 256, 0, stream>>>(counts, offsets, totals);
    k_bscan<<<1, 512, 0, stream>>>(totals, bucketBase);
    k_stage<<<NB_A, 256, 0, stream>>>(ei_ind, ei_uni, offsets, bucketBase, staging);
    k_binsort<<<NBUCK, 256, 0, stream>>>(staging, bucketBase, ssrc2, offs2);

    // ---- Industry GAT ----
    k_xl<<<NBLK64, 256, 0, stream>>>(Cenc, gi_w, gi_as, gi_ad, xl, a_src, a_dst, N);
    k_gat_agg<<<(N + 3) / 4, 256, 0, stream>>>(Cenc, xl, a_src, a_dst, offs2, ssrc2, gi_b, C_I, N);

    // ---- Universe GAT ----
    k_xl<<<NBLK64, 256, 0, stream>>>(C_I, gu_w, gu_as, gu_ad, xl, a_src, a_dst, N);
    k_gat_agg<<<(N + 3) / 4, 256, 0, stream>>>(C_I, xl, a_src, a_dst, offs2 + N, ssrc2, gu_b, C_U, N);

    // ---- Decoder + factor attention ----
    k_dec<<<NBLK64, 256, 0, stream>>>(Cenc, C_I, C_U, dec_w1, dec_b1, dec_w2, dec_b2, out_deep, N);
    k_fa<<<NBLK64, 256, 0, stream>>>(x, fa_w, fa_b, out_attn, N);
}

// Round 8
// 541.670 us; speedup vs baseline: 3.1953x; 1.1603x over previous
//
#include <hip/hip_runtime.h>
#include <hip/hip_bf16.h>
#include <hip/hip_fp16.h>
#include <math.h>

#define NNODES 50000
#define FDIM   128
#define HIDDIM 64
#define NEDGES 800000
#define NBLK64 782          // ceil(50000/64)
#define N2     (2*NNODES)
#define NB_A   256
#define CHUNK  6250         // 2*NEDGES / NB_A (exact)
#define NBUCK  391          // ceil(100000/256)
#define NBPAD  512

__device__ __forceinline__ float leakyf(float x) { return x > 0.f ? x : 0.2f * x; }
__device__ __forceinline__ float eluf(float x)   { return x > 0.f ? x : expm1f(x); }

#define FMA8(A, xv, wa, wb) \
    A[0] += xv * wa.x; A[1] += xv * wa.y; A[2] += xv * wa.z; A[3] += xv * wa.w; \
    A[4] += xv * wb.x; A[5] += xv * wb.y; A[6] += xv * wb.z; A[7] += xv * wb.w;

// ---------------- BatchNorm statistics ----------------
__global__ void k_bn_stats(const float* __restrict__ x, float* __restrict__ acc, int n) {
    int t = threadIdx.x;
    int f = t & 127, half = t >> 7;
    int rows_per_block = (n + gridDim.x - 1) / gridDim.x;
    int r0 = blockIdx.x * rows_per_block;
    int r1 = min(r0 + rows_per_block, n);
    float s = 0.f, s2 = 0.f;
    for (int r = r0 + half; r < r1; r += 2) {
        float v = x[(size_t)r * 128 + f];
        s += v; s2 += v * v;
    }
    __shared__ float ls[256], ls2[256];
    ls[t] = s; ls2[t] = s2;
    __syncthreads();
    if (t < 128) {
        s  = ls[t]  + ls[t + 128];
        s2 = ls2[t] + ls2[t + 128];
        atomicAdd(&acc[f], s);
        atomicAdd(&acc[128 + f], s2);
    }
}

__global__ void k_bn_final(const float* __restrict__ acc, const float* __restrict__ gamma,
                           const float* __restrict__ beta, float* __restrict__ ss, int n) {
    int f = threadIdx.x;
    if (f < 128) {
        float inv_n = 1.0f / (float)n;
        float mean = acc[f] * inv_n;
        float var  = acc[128 + f] * inv_n - mean * mean;
        float sc = gamma[f] * rsqrtf(var + 1e-5f);
        ss[f] = sc;
        ss[128 + f] = beta[f] - mean * sc;
    }
}

// ---------------- Fused BN + encoder, 64-row tile, prefetched weights ----------------
__launch_bounds__(256, 4)
__global__ void k_encoder(const float* __restrict__ x, const float* __restrict__ bnss,
                          const float* __restrict__ w1, const float* __restrict__ b1,
                          const float* __restrict__ w2, const float* __restrict__ b2,
                          float* __restrict__ Cenc, int n_nodes) {
    __shared__ float Xs[64][133];
    int t = threadIdx.x;
    int r0 = blockIdx.x * 64;
#pragma unroll
    for (int it = 0; it < 8; ++it) {
        int idx = it * 256 + t;
        int row = idx >> 5;
        int col = (idx & 31) * 4;
        float4 v = make_float4(0.f, 0.f, 0.f, 0.f);
        if (r0 + row < n_nodes) v = *(const float4*)(x + (size_t)(r0 + row) * 128 + col);
        float4 sc = *(const float4*)(bnss + col);
        float4 sh = *(const float4*)(bnss + 128 + col);
        Xs[row][col + 0] = v.x * sc.x + sh.x;
        Xs[row][col + 1] = v.y * sc.y + sh.y;
        Xs[row][col + 2] = v.z * sc.z + sh.z;
        Xs[row][col + 3] = v.w * sc.w + sh.w;
    }
    __syncthreads();
    int cg = t & 15, rsub = t >> 4;
    int c0 = cg * 8, rbase = rsub * 4;
    float acc[4][8];
    {
        float4 ba = *(const float4*)(b1 + c0);
        float4 bb = *(const float4*)(b1 + c0 + 4);
#pragma unroll
        for (int j = 0; j < 4; ++j) {
            acc[j][0] = ba.x; acc[j][1] = ba.y; acc[j][2] = ba.z; acc[j][3] = ba.w;
            acc[j][4] = bb.x; acc[j][5] = bb.y; acc[j][6] = bb.z; acc[j][7] = bb.w;
        }
    }
    {
        float4 wA[4], wB[4];
#pragma unroll
        for (int d = 0; d < 4; ++d) {
            wA[d] = *(const float4*)(w1 + d * 128 + c0);
            wB[d] = *(const float4*)(w1 + d * 128 + c0 + 4);
        }
        for (int k = 0; k < 128; k += 4) {
#pragma unroll
            for (int d = 0; d < 4; ++d) {
                int kn = (k + 4 + d) & 127;
                float4 na = *(const float4*)(w1 + kn * 128 + c0);
                float4 nb = *(const float4*)(w1 + kn * 128 + c0 + 4);
                float x0 = Xs[rbase + 0][k + d];
                float x1 = Xs[rbase + 1][k + d];
                float x2 = Xs[rbase + 2][k + d];
                float x3 = Xs[rbase + 3][k + d];
                FMA8(acc[0], x0, wA[d], wB[d])
                FMA8(acc[1], x1, wA[d], wB[d])
                FMA8(acc[2], x2, wA[d], wB[d])
                FMA8(acc[3], x3, wA[d], wB[d])
                wA[d] = na; wB[d] = nb;
            }
        }
    }
    __syncthreads();
#pragma unroll
    for (int j = 0; j < 4; ++j)
#pragma unroll
        for (int i = 0; i < 8; ++i)
            Xs[rbase + j][c0 + i] = fmaxf(acc[j][i], 0.f);
    __syncthreads();
    int cg2 = t & 7, rs2 = t >> 3;
    int c2 = cg2 * 8, r2 = rs2 * 2;
    float a2[2][8];
    {
        float4 ba = *(const float4*)(b2 + c2);
        float4 bb = *(const float4*)(b2 + c2 + 4);
#pragma unroll
        for (int j = 0; j < 2; ++j) {
            a2[j][0] = ba.x; a2[j][1] = ba.y; a2[j][2] = ba.z; a2[j][3] = ba.w;
            a2[j][4] = bb.x; a2[j][5] = bb.y; a2[j][6] = bb.z; a2[j][7] = bb.w;
        }
    }
    {
        float4 wA[4], wB[4];
#pragma unroll
        for (int d = 0; d < 4; ++d) {
            wA[d] = *(const float4*)(w2 + d * 64 + c2);
            wB[d] = *(const float4*)(w2 + d * 64 + c2 + 4);
        }
        for (int k = 0; k < 128; k += 4) {
#pragma unroll
            for (int d = 0; d < 4; ++d) {
                int kn = (k + 4 + d) & 127;
                float4 na = *(const float4*)(w2 + kn * 64 + c2);
                float4 nb = *(const float4*)(w2 + kn * 64 + c2 + 4);
                float h0 = Xs[r2 + 0][k + d];
                float h1 = Xs[r2 + 1][k + d];
                FMA8(a2[0], h0, wA[d], wB[d])
                FMA8(a2[1], h1, wA[d], wB[d])
                wA[d] = na; wB[d] = nb;
            }
        }
    }
#pragma unroll
    for (int j = 0; j < 2; ++j) {
        int row = r0 + r2 + j;
        if (row < n_nodes) {
            float* o = Cenc + (size_t)row * 64 + c2;
            *(float4*)o       = make_float4(fmaxf(a2[j][0], 0.f), fmaxf(a2[j][1], 0.f),
                                            fmaxf(a2[j][2], 0.f), fmaxf(a2[j][3], 0.f));
            *(float4*)(o + 4) = make_float4(fmaxf(a2[j][4], 0.f), fmaxf(a2[j][5], 0.f),
                                            fmaxf(a2[j][6], 0.f), fmaxf(a2[j][7], 0.f));
        }
    }
}

// ---------------- GAT: xl = Cin @ W (fp16 out) + fused attention logits ----------------
__launch_bounds__(256, 4)
__global__ void k_xl(const float* __restrict__ Cin, const float* __restrict__ Wg,
                     const float* __restrict__ attS, const float* __restrict__ attD,
                     __half* __restrict__ xl, float* __restrict__ asrc, float* __restrict__ adst,
                     int n_nodes) {
    __shared__ float Cs[64][65];
    int t = threadIdx.x;
    int r0 = blockIdx.x * 64;
#pragma unroll
    for (int it = 0; it < 4; ++it) {
        int idx = it * 256 + t;
        int row = idx >> 4;
        int col = (idx & 15) * 4;
        float4 v = make_float4(0.f, 0.f, 0.f, 0.f);
        if (r0 + row < n_nodes) v = *(const float4*)(Cin + (size_t)(r0 + row) * 64 + col);
        Cs[row][col + 0] = v.x; Cs[row][col + 1] = v.y;
        Cs[row][col + 2] = v.z; Cs[row][col + 3] = v.w;
    }
    __syncthreads();
    int cg = t & 15, rsub = t >> 4;
    int c0 = cg * 8, rbase = rsub * 4;
    float acc[4][8];
#pragma unroll
    for (int j = 0; j < 4; ++j)
#pragma unroll
        for (int i = 0; i < 8; ++i) acc[j][i] = 0.f;
    {
        float4 wA[4], wB[4];
#pragma unroll
        for (int d = 0; d < 4; ++d) {
            wA[d] = *(const float4*)(Wg + d * 128 + c0);
            wB[d] = *(const float4*)(Wg + d * 128 + c0 + 4);
        }
        for (int k = 0; k < 64; k += 4) {
#pragma unroll
            for (int d = 0; d < 4; ++d) {
                int kn = (k + 4 + d) & 63;
                float4 na = *(const float4*)(Wg + kn * 128 + c0);
                float4 nb = *(const float4*)(Wg + kn * 128 + c0 + 4);
                float x0 = Cs[rbase + 0][k + d];
                float x1 = Cs[rbase + 1][k + d];
                float x2 = Cs[rbase + 2][k + d];
                float x3 = Cs[rbase + 3][k + d];
                FMA8(acc[0], x0, wA[d], wB[d])
                FMA8(acc[1], x1, wA[d], wB[d])
                FMA8(acc[2], x2, wA[d], wB[d])
                FMA8(acc[3], x3, wA[d], wB[d])
                wA[d] = na; wB[d] = nb;
            }
        }
    }
    // write xl as fp16 (8 halves = 16B per thread)
#pragma unroll
    for (int j = 0; j < 4; ++j) {
        int row = r0 + rbase + j;
        if (row < n_nodes) {
            __half2 h4[4];
#pragma unroll
            for (int q = 0; q < 4; ++q)
                h4[q] = __float22half2_rn(make_float2(acc[j][2*q], acc[j][2*q+1]));
            *(float4*)(xl + (size_t)row * 128 + c0) = *(float4*)h4;
        }
    }
    int head = cg >> 3;
    const float* as_ = attS + head * 64 + (cg & 7) * 8;
    const float* ad_ = attD + head * 64 + (cg & 7) * 8;
    float4 sa = *(const float4*)as_,       sb = *(const float4*)(as_ + 4);
    float4 da = *(const float4*)ad_,       db = *(const float4*)(ad_ + 4);
    float ps[4], pd[4];
#pragma unroll
    for (int j = 0; j < 4; ++j) {
        ps[j] = acc[j][0]*sa.x + acc[j][1]*sa.y + acc[j][2]*sa.z + acc[j][3]*sa.w
              + acc[j][4]*sb.x + acc[j][5]*sb.y + acc[j][6]*sb.z + acc[j][7]*sb.w;
        pd[j] = acc[j][0]*da.x + acc[j][1]*da.y + acc[j][2]*da.z + acc[j][3]*da.w
              + acc[j][4]*db.x + acc[j][5]*db.y + acc[j][6]*db.z + acc[j][7]*db.w;
#pragma unroll
        for (int off = 1; off < 8; off <<= 1) {
            ps[j] += __shfl_xor(ps[j], off, 64);
            pd[j] += __shfl_xor(pd[j], off, 64);
        }
    }
    if ((cg & 7) == 0) {
#pragma unroll
        for (int j = 0; j < 4; ++j) {
            int row = r0 + rbase + j;
            if (row < n_nodes) {
                asrc[2 * row + head] = ps[j];
                adst[2 * row + head] = pd[j];
            }
        }
    }
}

// ================ CSR build via two-level counting sort ================
__launch_bounds__(256)
__global__ void k_hist(const int* __restrict__ ei_i, const int* __restrict__ ei_u,
                       int* __restrict__ counts) {
    __shared__ int hist[NBPAD];
    int t = threadIdx.x, blk = blockIdx.x;
    for (int i = t; i < NBPAD; i += 256) hist[i] = 0;
    __syncthreads();
    int p0 = blk * CHUNK;
    for (int k = 0; k < CHUNK; k += 256) {
        if (k + t < CHUNK) {
            int p = p0 + k + t;
            int d2 = (p < NEDGES) ? ei_i[NEDGES + p]
                                  : (NNODES + ei_u[NEDGES + (p - NEDGES)]);
            atomicAdd(&hist[d2 >> 8], 1);
        }
    }
    __syncthreads();
    for (int i = t; i < NBPAD; i += 256) counts[blk * NBPAD + i] = hist[i];
}

__launch_bounds__(256)
__global__ void k_rowscan(const int* __restrict__ counts, int* __restrict__ offsets,
                          int* __restrict__ totals) {
    __shared__ int sd[256];
    int b = blockIdx.x;
    int t = threadIdx.x;
    int v = counts[t * NBPAD + b];
    sd[t] = v;
    __syncthreads();
    for (int off = 1; off < 256; off <<= 1) {
        int u = (t >= off) ? sd[t - off] : 0;
        __syncthreads();
        sd[t] += u;
        __syncthreads();
    }
    offsets[t * NBPAD + b] = sd[t] - v;
    if (t == 255) totals[b] = sd[255];
}

__launch_bounds__(512)
__global__ void k_bscan(const int* __restrict__ totals, int* __restrict__ bucketBase) {
    __shared__ int sd[512];
    int t = threadIdx.x;
    int v = totals[t];
    sd[t] = v; __syncthreads();
    for (int off = 1; off < 512; off <<= 1) {
        int u = (t >= off) ? sd[t - off] : 0;
        __syncthreads();
        sd[t] += u;
        __syncthreads();
    }
    bucketBase[t] = sd[t] - v;
    if (t == 511) bucketBase[512] = sd[511];
}

// A3: LDS counting-sort per chunk (hist loaded from counts), burst-write staging
__launch_bounds__(256, 2)
__global__ void k_stage(const int* __restrict__ ei_i, const int* __restrict__ ei_u,
                        const int* __restrict__ counts,
                        const int* __restrict__ offsets, const int* __restrict__ bucketBase,
                        unsigned int* __restrict__ staging) {
    __shared__ int runstart[NBPAD];
    __shared__ int cursor[NBPAD];
    __shared__ int delta[NBPAD];
    __shared__ int sd[256];
    __shared__ unsigned int sorted[CHUNK];
    __shared__ unsigned short slotb[CHUNK];
    int t = threadIdx.x, blk = blockIdx.x;
    // load per-chunk histogram (computed by k_hist)
    int v0 = counts[blk * NBPAD + 2 * t];
    int v1 = counts[blk * NBPAD + 2 * t + 1];
    int s = v0 + v1;
    sd[t] = s; __syncthreads();
    for (int off = 1; off < 256; off <<= 1) {
        int u = (t >= off) ? sd[t - off] : 0;
        __syncthreads();
        sd[t] += u;
        __syncthreads();
    }
    int base = sd[t] - s;
    runstart[2 * t] = base;
    runstart[2 * t + 1] = base + v0;
    __syncthreads();
    for (int i = t; i < NBPAD; i += 256) {
        cursor[i] = runstart[i];
        delta[i] = bucketBase[i] + offsets[blk * NBPAD + i] - runstart[i];
    }
    __syncthreads();
    int p0 = blk * CHUNK;
    for (int k = 0; k < CHUNK; k += 256) {
        if (k + t < CHUNK) {
            int p = p0 + k + t;
            int src, d2;
            if (p < NEDGES) { src = ei_i[p]; d2 = ei_i[NEDGES + p]; }
            else { int q = p - NEDGES; src = ei_u[q]; d2 = NNODES + ei_u[NEDGES + q]; }
            int b = d2 >> 8;
            int pos = atomicAdd(&cursor[b], 1);
            sorted[pos] = ((unsigned)src << 8) | (unsigned)(d2 & 255);
            slotb[pos] = (unsigned short)b;
        }
    }
    __syncthreads();
    for (int k = t; k < CHUNK; k += 256) {
        int b = slotb[k];
        staging[delta[b] + k] = sorted[k];
    }
}

__launch_bounds__(256)
__global__ void k_binsort(const unsigned int* __restrict__ staging,
                          const int* __restrict__ bucketBase,
                          int* __restrict__ ssrc, int* __restrict__ offs2) {
    __shared__ int hist[256];
    __shared__ int cursor[256];
    __shared__ int sd[256];
    int b = blockIdx.x, t = threadIdx.x;
    int base = bucketBase[b];
    int cnt  = bucketBase[b + 1] - base;
    hist[t] = 0;
    __syncthreads();
    for (int p = t; p < cnt; p += 256)
        atomicAdd(&hist[staging[base + p] & 255u], 1);
    __syncthreads();
    int v = hist[t];
    sd[t] = v; __syncthreads();
    for (int off = 1; off < 256; off <<= 1) {
        int u = (t >= off) ? sd[t - off] : 0;
        __syncthreads();
        sd[t] += u;
        __syncthreads();
    }
    int excl = sd[t] - v;
    cursor[t] = excl;
    int d2 = b * 256 + t;
    if (d2 <= N2) offs2[d2] = base + excl;
    __syncthreads();
    for (int p = t; p < cnt; p += 256) {
        unsigned int e = staging[base + p];
        int pos = atomicAdd(&cursor[e & 255u], 1);
        ssrc[base + pos] = (int)(e >> 8);
    }
}

// ---------------- GAT aggregation: one wave per dst node, fp16 gather ----------------
__launch_bounds__(256)
__global__ void k_gat_agg(const float* __restrict__ Cin, const __half* __restrict__ xl,
                          const float* __restrict__ asrc, const float* __restrict__ adst,
                          const int* __restrict__ offs, const int* __restrict__ ssrc,
                          const float* __restrict__ bias, float* __restrict__ Cout,
                          int n_nodes) {
    int wid = (blockIdx.x * blockDim.x + threadIdx.x) >> 6;
    int lane = threadIdx.x & 63;
    if (wid >= n_nodes) return;
    int n = wid;
    int h = lane >> 5;
    int beg = offs[n], end = offs[n + 1];
    float adh = adst[2 * n + h];
    const __half2* xh = (const __half2*)xl;
    // self loop
    float ee = __expf(leakyf(asrc[2 * n + h] + adh));
    float2 v = __half22float2(xh[(size_t)n * 64 + lane]);
    float acc0 = ee * v.x, acc1 = ee * v.y, dn = ee;
    int i = beg;
    for (; i + 1 < end; i += 2) {
        int s0 = ssrc[i], s1 = ssrc[i + 1];
        __half2 u0 = xh[(size_t)s0 * 64 + lane];
        __half2 u1 = xh[(size_t)s1 * 64 + lane];
        float e0 = __expf(leakyf(asrc[2 * s0 + h] + adh));
        float e1 = __expf(leakyf(asrc[2 * s1 + h] + adh));
        float2 f0 = __half22float2(u0);
        float2 f1 = __half22float2(u1);
        acc0 += e0 * f0.x + e1 * f1.x;
        acc1 += e0 * f0.y + e1 * f1.y;
        dn   += e0 + e1;
    }
    if (i < end) {
        int s0 = ssrc[i];
        __half2 u0 = xh[(size_t)s0 * 64 + lane];
        float e0 = __expf(leakyf(asrc[2 * s0 + h] + adh));
        float2 f0 = __half22float2(u0);
        acc0 += e0 * f0.x; acc1 += e0 * f0.y; dn += e0;
    }
    float inv = 1.0f / dn;
    float o0 = acc0 * inv, o1 = acc1 * inv;
    float p0 = __shfl_xor(o0, 32, 64);
    float p1 = __shfl_xor(o1, 32, 64);
    if (lane < 32) {
        int c0 = 2 * lane;
        float hv0 = eluf(0.5f * (o0 + p0) + bias[c0]);
        float hv1 = eluf(0.5f * (o1 + p1) + bias[c0 + 1]);
        float2 cv = *(const float2*)(Cin + (size_t)n * 64 + c0);
        *(float2*)(Cout + (size_t)n * 64 + c0) = make_float2(cv.x - hv0, cv.y - hv1);
    }
}

// ---------------- Decoder ----------------
__launch_bounds__(256, 3)
__global__ void k_dec(const float* __restrict__ Cenc, const float* __restrict__ CI,
                      const float* __restrict__ CU, const float* __restrict__ w1,
                      const float* __restrict__ b1, const float* __restrict__ w2,
                      const float* __restrict__ b2, float* __restrict__ out, int n_nodes) {
    __shared__ float Fs[64][193];
    int t = threadIdx.x;
    int r0 = blockIdx.x * 64;
    const float* srcs[3] = {Cenc, CI, CU};
#pragma unroll
    for (int s = 0; s < 3; ++s) {
        const float* src = srcs[s];
#pragma unroll
        for (int it = 0; it < 4; ++it) {
            int idx = it * 256 + t;
            int row = idx >> 4;
            int col = (idx & 15) * 4;
            float4 v = make_float4(0.f, 0.f, 0.f, 0.f);
            if (r0 + row < n_nodes) v = *(const float4*)(src + (size_t)(r0 + row) * 64 + col);
            Fs[row][s * 64 + col + 0] = v.x; Fs[row][s * 64 + col + 1] = v.y;
            Fs[row][s * 64 + col + 2] = v.z; Fs[row][s * 64 + col + 3] = v.w;
        }
    }
    __syncthreads();
    int cg = t & 7, rs = t >> 3;
    int c0 = cg * 8, r2 = rs * 2;
    float acc[2][8];
    {
        float4 ba = *(const float4*)(b1 + c0);
        float4 bb = *(const float4*)(b1 + c0 + 4);
#pragma unroll
        for (int j = 0; j < 2; ++j) {
            acc[j][0] = ba.x; acc[j][1] = ba.y; acc[j][2] = ba.z; acc[j][3] = ba.w;
            acc[j][4] = bb.x; acc[j][5] = bb.y; acc[j][6] = bb.z; acc[j][7] = bb.w;
        }
    }
    {
        float4 wA[4], wB[4];
#pragma unroll
        for (int d = 0; d < 4; ++d) {
            wA[d] = *(const float4*)(w1 + d * 64 + c0);
            wB[d] = *(const float4*)(w1 + d * 64 + c0 + 4);
        }
        for (int k = 0; k < 192; k += 4) {
#pragma unroll
            for (int d = 0; d < 4; ++d) {
                int kn = k + 4 + d; if (kn > 191) kn = 191;
                float4 na = *(const float4*)(w1 + kn * 64 + c0);
                float4 nb = *(const float4*)(w1 + kn * 64 + c0 + 4);
                float f0 = Fs[r2 + 0][k + d];
                float f1 = Fs[r2 + 1][k + d];
                FMA8(acc[0], f0, wA[d], wB[d])
                FMA8(acc[1], f1, wA[d], wB[d])
                wA[d] = na; wB[d] = nb;
            }
        }
    }
    float4 w2a = *(const float4*)(w2 + c0);
    float4 w2b = *(const float4*)(w2 + c0 + 4);
    float b2v = b2[0];
#pragma unroll
    for (int j = 0; j < 2; ++j) {
        float p = leakyf(acc[j][0])*w2a.x + leakyf(acc[j][1])*w2a.y
                + leakyf(acc[j][2])*w2a.z + leakyf(acc[j][3])*w2a.w
                + leakyf(acc[j][4])*w2b.x + leakyf(acc[j][5])*w2b.y
                + leakyf(acc[j][6])*w2b.z + leakyf(acc[j][7])*w2b.w;
#pragma unroll
        for (int off = 1; off < 8; off <<= 1) p += __shfl_xor(p, off, 64);
        int row = r0 + r2 + j;
        if (cg == 0 && row < n_nodes) out[row] = p + b2v;
    }
}

// ---------------- Factor attention ----------------
__launch_bounds__(256, 4)
__global__ void k_fa(const float* __restrict__ x, const float* __restrict__ w,
                     const float* __restrict__ b, float* __restrict__ attn, int n_nodes) {
    __shared__ float Xs[64][133];
    int t = threadIdx.x;
    int r0 = blockIdx.x * 64;
#pragma unroll
    for (int it = 0; it < 8; ++it) {
        int idx = it * 256 + t;
        int row = idx >> 5;
        int col = (idx & 31) * 4;
        float4 v = make_float4(0.f, 0.f, 0.f, 0.f);
        if (r0 + row < n_nodes) v = *(const float4*)(x + (size_t)(r0 + row) * 128 + col);
        Xs[row][col + 0] = v.x; Xs[row][col + 1] = v.y;
        Xs[row][col + 2] = v.z; Xs[row][col + 3] = v.w;
    }
    __syncthreads();
    int cg = t & 15, rsub = t >> 4;
    int c0 = cg * 8, rbase = rsub * 4;
    float acc[4][8];
    {
        float4 ba = *(const float4*)(b + c0);
        float4 bb = *(const float4*)(b + c0 + 4);
#pragma unroll
        for (int j = 0; j < 4; ++j) {
            acc[j][0] = ba.x; acc[j][1] = ba.y; acc[j][2] = ba.z; acc[j][3] = ba.w;
            acc[j][4] = bb.x; acc[j][5] = bb.y; acc[j][6] = bb.z; acc[j][7] = bb.w;
        }
    }
    {
        float4 wA[4], wB[4];
#pragma unroll
        for (int d = 0; d < 4; ++d) {
            wA[d] = *(const float4*)(w + d * 128 + c0);
            wB[d] = *(const float4*)(w + d * 128 + c0 + 4);
        }
        for (int k = 0; k < 128; k += 4) {
#pragma unroll
            for (int d = 0; d < 4; ++d) {
                int kn = (k + 4 + d) & 127;
                float4 na = *(const float4*)(w + kn * 128 + c0);
                float4 nb = *(const float4*)(w + kn * 128 + c0 + 4);
                float x0 = Xs[rbase + 0][k + d];
                float x1 = Xs[rbase + 1][k + d];
                float x2 = Xs[rbase + 2][k + d];
                float x3 = Xs[rbase + 3][k + d];
                FMA8(acc[0], x0, wA[d], wB[d])
                FMA8(acc[1], x1, wA[d], wB[d])
                FMA8(acc[2], x2, wA[d], wB[d])
                FMA8(acc[3], x3, wA[d], wB[d])
                wA[d] = na; wB[d] = nb;
            }
        }
    }
#pragma unroll
    for (int j = 0; j < 4; ++j) {
        float m = -1e30f;
#pragma unroll
        for (int i = 0; i < 8; ++i) {
            acc[j][i] = leakyf(acc[j][i]);
            m = fmaxf(m, acc[j][i]);
        }
#pragma unroll
        for (int off = 1; off < 16; off <<= 1) m = fmaxf(m, __shfl_xor(m, off, 64));
        float s = 0.f;
#pragma unroll
        for (int i = 0; i < 8; ++i) {
            acc[j][i] = __expf(acc[j][i] - m);
            s += acc[j][i];
        }
#pragma unroll
        for (int off = 1; off < 16; off <<= 1) s += __shfl_xor(s, off, 64);
        float inv = 1.0f / s;
        int row = r0 + rbase + j;
        if (row < n_nodes) {
            float* o = attn + (size_t)row * 128 + c0;
            *(float4*)o       = make_float4(acc[j][0]*inv, acc[j][1]*inv, acc[j][2]*inv, acc[j][3]*inv);
            *(float4*)(o + 4) = make_float4(acc[j][4]*inv, acc[j][5]*inv, acc[j][6]*inv, acc[j][7]*inv);
        }
    }
}

extern "C" void kernel_launch(void* const* d_in, const int* in_sizes, int n_in,
                              void* d_out, int out_size, void* d_ws, size_t ws_size,
                              hipStream_t stream) {
    const float* x        = (const float*)d_in[0];
    const int*   ei_ind   = (const int*)d_in[1];
    const int*   ei_uni   = (const int*)d_in[2];
    const float* bn_gamma = (const float*)d_in[3];
    const float* bn_beta  = (const float*)d_in[4];
    const float* enc_w1   = (const float*)d_in[5];
    const float* enc_b1   = (const float*)d_in[6];
    const float* enc_w2   = (const float*)d_in[7];
    const float* enc_b2   = (const float*)d_in[8];
    const float* gi_w     = (const float*)d_in[9];
    const float* gi_as    = (const float*)d_in[10];
    const float* gi_ad    = (const float*)d_in[11];
    const float* gi_b     = (const float*)d_in[12];
    const float* gu_w     = (const float*)d_in[13];
    const float* gu_as    = (const float*)d_in[14];
    const float* gu_ad    = (const float*)d_in[15];
    const float* gu_b     = (const float*)d_in[16];
    const float* dec_w1   = (const float*)d_in[17];
    const float* dec_b1   = (const float*)d_in[18];
    const float* dec_w2   = (const float*)d_in[19];
    const float* dec_b2   = (const float*)d_in[20];
    const float* fa_w     = (const float*)d_in[21];
    const float* fa_b     = (const float*)d_in[22];

    const int N = NNODES, E = NEDGES;

    float* Cenc  = (float*)d_ws;
    float* C_I   = Cenc + (size_t)N * 64;
    float* C_U   = C_I + (size_t)N * 64;
    float* xlf   = C_U + (size_t)N * 64;       // region sized N*128 floats; used as fp16 (half needed)
    float* a_src = xlf + (size_t)N * 128;
    float* a_dst = a_src + (size_t)N * 2;
    float* bnacc = a_dst + (size_t)N * 2;
    float* bnss  = bnacc + 256;
    int* offs2      = (int*)(bnss + 256);
    int* ssrc2      = offs2 + (N2 + 1);
    int* counts     = ssrc2 + 2 * E;
    int* offsets    = counts + NB_A * NBPAD;
    int* totals     = offsets + NB_A * NBPAD;
    int* bucketBase = totals + NBPAD;          // 513 ints
    __half* xl = (__half*)xlf;
    unsigned int* staging = (unsigned int*)(xlf + (size_t)N * 64); // upper half of xl region (CSR build precedes k_xl)

    float* out_deep = (float*)d_out;
    float* out_attn = out_deep + N;

    // ---- BatchNorm stats ----
    hipMemsetAsync(bnacc, 0, 256 * sizeof(float), stream);
    k_bn_stats<<<256, 256, 0, stream>>>(x, bnacc, N);
    k_bn_final<<<1, 128, 0, stream>>>(bnacc, bn_gamma, bn_beta, bnss, N);

    // ---- Encoder ----
    k_encoder<<<NBLK64, 256, 0, stream>>>(x, bnss, enc_w1, enc_b1, enc_w2, enc_b2, Cenc, N);

    // ---- CSR build (two-level counting sort, both graphs merged) ----
    k_hist<<<NB_A, 256, 0, stream>>>(ei_ind, ei_uni, counts);
    k_rowscan<<<NBPAD, 256, 0, stream>>>(counts, offsets, totals);
    k_bscan<<<1, 512, 0, stream>>>(totals, bucketBase);
    k_stage<<<NB_A, 256, 0, stream>>>(ei_ind, ei_uni, counts, offsets, bucketBase, staging);
    k_binsort<<<NBUCK, 256, 0, stream>>>(staging, bucketBase, ssrc2, offs2);

    // ---- Industry GAT ----
    k_xl<<<NBLK64, 256, 0, stream>>>(Cenc, gi_w, gi_as, gi_ad, xl, a_src, a_dst, N);
    k_gat_agg<<<(N + 3) / 4, 256, 0, stream>>>(Cenc, xl, a_src, a_dst, offs2, ssrc2, gi_b, C_I, N);

    // ---- Universe GAT ----
    k_xl<<<NBLK64, 256, 0, stream>>>(C_I, gu_w, gu_as, gu_ad, xl, a_src, a_dst, N);
    k_gat_agg<<<(N + 3) / 4, 256, 0, stream>>>(C_I, xl, a_src, a_dst, offs2 + N, ssrc2, gu_b, C_U, N);

    // ---- Decoder + factor attention ----
    k_dec<<<NBLK64, 256, 0, stream>>>(Cenc, C_I, C_U, dec_w1, dec_b1, dec_w2, dec_b2, out_deep, N);
    k_fa<<<NBLK64, 256, 0, stream>>>(x, fa_w, fa_b, out_attn, N);
}